// Round 1
// baseline (1581.274 us; speedup 1.0000x reference)
//
#include <hip/hip_runtime.h>

#define NN 50000
#define EE 800000
#define DD 128
#define BN_EPS 1e-5f
#define TR 64
#define TC 64

// ---------------------------------------------------------------------------
// K0: h0 = (1+eps)*x, and block 0 zeros the BN accumulator region.
// stats layout (floats): [0:128) sum1 [128:256) sumsq1 [256:384) scale1
// [384:512) shift1 [512:640) sum2 [640:768) sumsq2 [768:896) scale2 [896:1024) shift2
// ---------------------------------------------------------------------------
__global__ __launch_bounds__(256) void k_init(const float* __restrict__ x,
                                              const float* __restrict__ eps,
                                              float* __restrict__ h0,
                                              float* __restrict__ stats) {
  const int gid = blockIdx.x * 256 + threadIdx.x;  // over N*D/4 float4s
  if (blockIdx.x == 0) {
    stats[threadIdx.x] = 0.0f;        // sum1 + sumsq1
    stats[512 + threadIdx.x] = 0.0f;  // sum2 + sumsq2
  }
  const float s = 1.0f + eps[0];
  float4 v = ((const float4*)x)[gid];
  v.x *= s; v.y *= s; v.z *= s; v.w *= s;
  ((float4*)h0)[gid] = v;
}

// ---------------------------------------------------------------------------
// K1: scatter-add. 32 threads per edge, each handles one float4 chunk.
// ---------------------------------------------------------------------------
__global__ __launch_bounds__(256) void k_scatter(const float* __restrict__ x,
                                                 const int* __restrict__ rows,
                                                 const int* __restrict__ cols,
                                                 float* __restrict__ h0) {
  const long long gtid = (long long)blockIdx.x * 256 + threadIdx.x;
  const int e = (int)(gtid >> 5);
  const int j = (int)(gtid & 31);
  if (e >= EE) return;
  const int r = rows[e];
  const int c = cols[e];
  const float4 v = ((const float4*)(x + (long long)c * DD))[j];
  float* dst = h0 + (long long)r * DD + j * 4;
  atomicAdd(dst + 0, v.x);
  atomicAdd(dst + 1, v.y);
  atomicAdd(dst + 2, v.z);
  atomicAdd(dst + 3, v.w);
}

// ---------------------------------------------------------------------------
// K2: fused GEMM: out[n][c] = sum_k act(in[n][k]) * W[c][k] + bias[c]
//   act = identity, or relu(ascale[k]*v + ashift[k]) when ascale != nullptr
// Also accumulates per-column sum / sumsq of out (for BatchNorm stats).
// Tile: 64 rows x 64 cols per block, 256 threads, 4x4 register tile.
// LDS layouts transposed to [k][r] / [k][c] so compute reads are b128.
// ---------------------------------------------------------------------------
__global__ __launch_bounds__(256) void k_gemm(const float* __restrict__ in,
                                              const float* __restrict__ W,
                                              const float* __restrict__ bias,
                                              const float* __restrict__ ascale,
                                              const float* __restrict__ ashift,
                                              float* __restrict__ out,
                                              float* __restrict__ gsum,
                                              float* __restrict__ gsumsq) {
  __shared__ __align__(16) float sIn[DD][TR];
  __shared__ __align__(16) float sW[DD][TC];
  __shared__ float bsum[TC];
  __shared__ float bsq[TC];

  const int tid = threadIdx.x;
  const int row0 = blockIdx.x * TR;
  const int c0 = blockIdx.y * TC;

  // ---- stage tiles (transposed). lanes vary over r -> conflict-free writes,
  //      global reads are 16B/lane within a row; the 8 iterations cover the
  //      full 512B row so fetched lines are fully consumed via L1.
  {
    const int r = tid & 63;
    const int kc0 = tid >> 6;  // 0..3
    const long long grow = (long long)row0 + r;
    const bool valid = grow < NN;
    const float* gin = in + grow * DD;
    const float* gw = W + (long long)(c0 + r) * DD;
#pragma unroll
    for (int it = 0; it < 8; ++it) {
      const int k = (kc0 + it * 4) * 4;  // 0..124 step 4
      float4 v = make_float4(0.f, 0.f, 0.f, 0.f);
      if (valid) {
        v = *(const float4*)(gin + k);
        if (ascale) {
          const float4 sc = *(const float4*)(ascale + k);
          const float4 sh = *(const float4*)(ashift + k);
          v.x = fmaxf(fmaf(sc.x, v.x, sh.x), 0.f);
          v.y = fmaxf(fmaf(sc.y, v.y, sh.y), 0.f);
          v.z = fmaxf(fmaf(sc.z, v.z, sh.z), 0.f);
          v.w = fmaxf(fmaf(sc.w, v.w, sh.w), 0.f);
        }
      }
      sIn[k + 0][r] = v.x;
      sIn[k + 1][r] = v.y;
      sIn[k + 2][r] = v.z;
      sIn[k + 3][r] = v.w;
      const float4 w = *(const float4*)(gw + k);
      sW[k + 0][r] = w.x;
      sW[k + 1][r] = w.y;
      sW[k + 2][r] = w.z;
      sW[k + 3][r] = w.w;
    }
  }
  if (tid < TC) {
    bsum[tid] = 0.f;
    bsq[tid] = 0.f;
  }
  __syncthreads();

  // ---- compute: 4 rows x 4 cols per thread
  const int rx = tid >> 4;  // 0..15
  const int cx = tid & 15;  // 0..15
  float acc[4][4] = {};
#pragma unroll 8
  for (int k = 0; k < DD; ++k) {
    const float4 a = *(const float4*)&sIn[k][rx * 4];
    const float4 b = *(const float4*)&sW[k][cx * 4];
    acc[0][0] = fmaf(a.x, b.x, acc[0][0]);
    acc[0][1] = fmaf(a.x, b.y, acc[0][1]);
    acc[0][2] = fmaf(a.x, b.z, acc[0][2]);
    acc[0][3] = fmaf(a.x, b.w, acc[0][3]);
    acc[1][0] = fmaf(a.y, b.x, acc[1][0]);
    acc[1][1] = fmaf(a.y, b.y, acc[1][1]);
    acc[1][2] = fmaf(a.y, b.z, acc[1][2]);
    acc[1][3] = fmaf(a.y, b.w, acc[1][3]);
    acc[2][0] = fmaf(a.z, b.x, acc[2][0]);
    acc[2][1] = fmaf(a.z, b.y, acc[2][1]);
    acc[2][2] = fmaf(a.z, b.z, acc[2][2]);
    acc[2][3] = fmaf(a.z, b.w, acc[2][3]);
    acc[3][0] = fmaf(a.w, b.x, acc[3][0]);
    acc[3][1] = fmaf(a.w, b.y, acc[3][1]);
    acc[3][2] = fmaf(a.w, b.z, acc[3][2]);
    acc[3][3] = fmaf(a.w, b.w, acc[3][3]);
  }

  // ---- epilogue: +bias, store, per-column partial sums for BN stats
  const float4 bv = *(const float4*)(bias + c0 + cx * 4);
  float s0 = 0.f, s1 = 0.f, s2 = 0.f, s3 = 0.f;
  float q0 = 0.f, q1 = 0.f, q2 = 0.f, q3 = 0.f;
#pragma unroll
  for (int i = 0; i < 4; ++i) {
    const int row = row0 + rx * 4 + i;
    if (row < NN) {
      float4 o;
      o.x = acc[i][0] + bv.x;
      o.y = acc[i][1] + bv.y;
      o.z = acc[i][2] + bv.z;
      o.w = acc[i][3] + bv.w;
      *(float4*)(out + (long long)row * DD + c0 + cx * 4) = o;
      s0 += o.x; q0 += o.x * o.x;
      s1 += o.y; q1 += o.y * o.y;
      s2 += o.z; q2 += o.z * o.z;
      s3 += o.w; q3 += o.w * o.w;
    }
  }
  atomicAdd(&bsum[cx * 4 + 0], s0);
  atomicAdd(&bsum[cx * 4 + 1], s1);
  atomicAdd(&bsum[cx * 4 + 2], s2);
  atomicAdd(&bsum[cx * 4 + 3], s3);
  atomicAdd(&bsq[cx * 4 + 0], q0);
  atomicAdd(&bsq[cx * 4 + 1], q1);
  atomicAdd(&bsq[cx * 4 + 2], q2);
  atomicAdd(&bsq[cx * 4 + 3], q3);
  __syncthreads();
  if (tid < TC) {
    atomicAdd(&gsum[c0 + tid], bsum[tid]);
    atomicAdd(&gsumsq[c0 + tid], bsq[tid]);
  }
}

// ---------------------------------------------------------------------------
// K3: BN stats -> per-column scale/shift.  biased variance, training mode.
// ---------------------------------------------------------------------------
__global__ void k_bnstats(const float* __restrict__ sum,
                          const float* __restrict__ sumsq,
                          const float* __restrict__ gamma,
                          const float* __restrict__ beta,
                          float* __restrict__ scale,
                          float* __restrict__ shift) {
  const int c = threadIdx.x;
  const float inv_n = 1.0f / (float)NN;
  const float mean = sum[c] * inv_n;
  const float var = sumsq[c] * inv_n - mean * mean;
  const float sc = gamma[c] * rsqrtf(var + BN_EPS);
  scale[c] = sc;
  shift[c] = beta[c] - mean * sc;
}

// ---------------------------------------------------------------------------
// K4: final BN + ReLU elementwise: out = relu(scale[c]*in + shift[c])
// ---------------------------------------------------------------------------
__global__ __launch_bounds__(256) void k_bnrelu(const float* __restrict__ in,
                                                const float* __restrict__ scale,
                                                const float* __restrict__ shift,
                                                float* __restrict__ out) {
  const int gid = blockIdx.x * 256 + threadIdx.x;  // over N*D/4 float4s
  const int c = (gid & 31) * 4;                    // 32 float4s per row
  float4 v = ((const float4*)in)[gid];
  const float4 sc = *(const float4*)(scale + c);
  const float4 sh = *(const float4*)(shift + c);
  v.x = fmaxf(fmaf(sc.x, v.x, sh.x), 0.f);
  v.y = fmaxf(fmaf(sc.y, v.y, sh.y), 0.f);
  v.z = fmaxf(fmaf(sc.z, v.z, sh.z), 0.f);
  v.w = fmaxf(fmaf(sc.w, v.w, sh.w), 0.f);
  ((float4*)out)[gid] = v;
}

// ---------------------------------------------------------------------------
extern "C" void kernel_launch(void* const* d_in, const int* in_sizes, int n_in,
                              void* d_out, int out_size, void* d_ws, size_t ws_size,
                              hipStream_t stream) {
  const float* x = (const float*)d_in[0];
  const int* ei = (const int*)d_in[1];  // [2][E]: rows then cols
  const float* eps = (const float*)d_in[2];
  const float* W1 = (const float*)d_in[3];
  const float* b1 = (const float*)d_in[4];
  const float* g1 = (const float*)d_in[5];
  const float* be1 = (const float*)d_in[6];
  const float* W2 = (const float*)d_in[7];
  const float* b2 = (const float*)d_in[8];
  const float* g2 = (const float*)d_in[9];
  const float* be2 = (const float*)d_in[10];
  float* out = (float*)d_out;

  float* h0 = (float*)d_ws;                        // N*D floats (agg, later h2_pre)
  float* stats = h0 + (size_t)NN * DD;             // 1024 floats
  float* sum1 = stats + 0;
  float* sumsq1 = stats + 128;
  float* scale1 = stats + 256;
  float* shift1 = stats + 384;
  float* sum2 = stats + 512;
  float* sumsq2 = stats + 640;
  float* scale2 = stats + 768;
  float* shift2 = stats + 896;

  const int ew_blocks = (NN * DD / 4) / 256;  // 6250

  // h0 = (1+eps)*x ; zero BN accumulators
  k_init<<<ew_blocks, 256, 0, stream>>>(x, eps, h0, stats);
  // h0 += scatter-add of x rows
  k_scatter<<<(EE * 32) / 256, 256, 0, stream>>>(x, ei, ei + EE, h0);

  dim3 gg((NN + TR - 1) / TR, DD / TC);
  // GEMM1: d_out <- h0 @ W1^T + b1 (pre-BN), stats1
  k_gemm<<<gg, 256, 0, stream>>>(h0, W1, b1, nullptr, nullptr, out, sum1, sumsq1);
  k_bnstats<<<1, 128, 0, stream>>>(sum1, sumsq1, g1, be1, scale1, shift1);
  // GEMM2: h0 <- relu(BN1(d_out)) @ W2^T + b2 (pre-BN), stats2
  k_gemm<<<gg, 256, 0, stream>>>(out, W2, b2, scale1, shift1, h0, sum2, sumsq2);
  k_bnstats<<<1, 128, 0, stream>>>(sum2, sumsq2, g2, be2, scale2, shift2);
  // d_out <- relu(BN2(h0))
  k_bnrelu<<<ew_blocks, 256, 0, stream>>>(h0, scale2, shift2, out);
}

// Round 2
// 483.335 us; speedup vs baseline: 3.2716x; 3.2716x over previous
//
#include <hip/hip_runtime.h>

#define NN 50000
#define EE 800000
#define DD 128
#define BN_EPS 1e-5f
#define TR 64
#define TC 64
#define SCAN_T 1024
#define SCAN_C 49  // ceil(50000/1024)

// ---------------------------------------------------------------------------
// Scratch plan:
//   d_out (12.8M floats) doubles as int scratch for the CSR build; it is dead
//   until GEMM1 writes it (stream-ordered after k_agg consumes the scratch).
//     offs   : [0, NN+1)          exclusive row offsets
//     cnt    : [50008, +NN)       per-row in-degree
//     cursor : [100016, +NN)      running placement cursor (copy of offs)
//     sc     : [150024, +EE)      column ids sorted by destination row
//   d_ws: h0 (N*D floats) + stats (1024 floats)
// ---------------------------------------------------------------------------

// K0: zero in-degree counters + BN stat accumulators
__global__ __launch_bounds__(256) void k_zero(int* __restrict__ cnt,
                                              float* __restrict__ stats) {
  const int gid = blockIdx.x * 256 + threadIdx.x;
  if (gid < NN) cnt[gid] = 0;
  if (gid < 1024) stats[gid] = 0.0f;
}

// K1: in-degree histogram (int atomics on L2-resident 200KB array)
__global__ __launch_bounds__(256) void k_hist(const int* __restrict__ rows,
                                              int* __restrict__ cnt) {
  const int e = blockIdx.x * 256 + threadIdx.x;
  if (e < EE) atomicAdd(&cnt[rows[e]], 1);
}

// K2: single-block exclusive scan over 50000 counts -> offs, cursor
__global__ __launch_bounds__(SCAN_T) void k_scan(const int* __restrict__ cnt,
                                                 int* __restrict__ offs,
                                                 int* __restrict__ cursor) {
  __shared__ int part[SCAN_T];
  const int t = threadIdx.x;
  const int i0 = t * SCAN_C;
  int n = NN - i0;
  n = n < 0 ? 0 : (n > SCAN_C ? SCAN_C : n);
  int s = 0;
  for (int k = 0; k < n; ++k) s += cnt[i0 + k];
  part[t] = s;
  __syncthreads();
  for (int off = 1; off < SCAN_T; off <<= 1) {
    const int v = (t >= off) ? part[t - off] : 0;
    __syncthreads();
    part[t] += v;
    __syncthreads();
  }
  int run = part[t] - s;  // exclusive base for this chunk
  for (int k = 0; k < n; ++k) {
    offs[i0 + k] = run;
    cursor[i0 + k] = run;
    run += cnt[i0 + k];
  }
  if (t == SCAN_T - 1) offs[NN] = part[SCAN_T - 1];
}

// K3: place column ids into destination-sorted order
__global__ __launch_bounds__(256) void k_place(const int* __restrict__ rows,
                                               const int* __restrict__ cols,
                                               int* __restrict__ cursor,
                                               int* __restrict__ sc) {
  const int e = blockIdx.x * 256 + threadIdx.x;
  if (e < EE) {
    const int pos = atomicAdd(&cursor[rows[e]], 1);
    sc[pos] = cols[e];
  }
}

// K4: gather-based aggregation. One 32-lane group per row; lane j owns
// float4 chunk j. h0[v] = (1+eps)*x[v] + sum_{u in N(v)} x[u].
// Each x-row access is a fully-coalesced 512B read; one 512B store per row.
__global__ __launch_bounds__(256) void k_agg(const float* __restrict__ x,
                                             const float* __restrict__ eps,
                                             const int* __restrict__ offs,
                                             const int* __restrict__ sc,
                                             float* __restrict__ h0) {
  const int g = threadIdx.x >> 5;  // 0..7: row group within block
  const int j = threadIdx.x & 31;  // float4 chunk within row
  const int v = blockIdx.x * 8 + g;  // 6250*8 == 50000 exactly
  const int beg = offs[v];
  const int end = offs[v + 1];
  const float s = 1.0f + eps[0];
  float4 acc = ((const float4*)(x + (size_t)v * DD))[j];
  acc.x *= s; acc.y *= s; acc.z *= s; acc.w *= s;
  int i = beg;
  for (; i + 2 <= end; i += 2) {  // unroll 2: both row loads in flight
    const int u0 = sc[i];
    const int u1 = sc[i + 1];
    const float4 a = ((const float4*)(x + (size_t)u0 * DD))[j];
    const float4 b = ((const float4*)(x + (size_t)u1 * DD))[j];
    acc.x += a.x + b.x;
    acc.y += a.y + b.y;
    acc.z += a.z + b.z;
    acc.w += a.w + b.w;
  }
  if (i < end) {
    const int u = sc[i];
    const float4 a = ((const float4*)(x + (size_t)u * DD))[j];
    acc.x += a.x; acc.y += a.y; acc.z += a.z; acc.w += a.w;
  }
  ((float4*)(h0 + (size_t)v * DD))[j] = acc;
}

// ---------------------------------------------------------------------------
// K5: fused GEMM: out[n][c] = sum_k act(in[n][k]) * W[c][k] + bias[c]
//   act = identity, or relu(ascale[k]*v + ashift[k]) when ascale != nullptr
// Also accumulates per-column sum / sumsq of out (for BatchNorm stats).
// ---------------------------------------------------------------------------
__global__ __launch_bounds__(256) void k_gemm(const float* __restrict__ in,
                                              const float* __restrict__ W,
                                              const float* __restrict__ bias,
                                              const float* __restrict__ ascale,
                                              const float* __restrict__ ashift,
                                              float* __restrict__ out,
                                              float* __restrict__ gsum,
                                              float* __restrict__ gsumsq) {
  __shared__ __align__(16) float sIn[DD][TR];
  __shared__ __align__(16) float sW[DD][TC];
  __shared__ float bsum[TC];
  __shared__ float bsq[TC];

  const int tid = threadIdx.x;
  const int row0 = blockIdx.x * TR;
  const int c0 = blockIdx.y * TC;

  {
    const int r = tid & 63;
    const int kc0 = tid >> 6;  // 0..3
    const long long grow = (long long)row0 + r;
    const bool valid = grow < NN;
    const float* gin = in + grow * DD;
    const float* gw = W + (long long)(c0 + r) * DD;
#pragma unroll
    for (int it = 0; it < 8; ++it) {
      const int k = (kc0 + it * 4) * 4;  // 0..124 step 4
      float4 v = make_float4(0.f, 0.f, 0.f, 0.f);
      if (valid) {
        v = *(const float4*)(gin + k);
        if (ascale) {
          const float4 sc = *(const float4*)(ascale + k);
          const float4 sh = *(const float4*)(ashift + k);
          v.x = fmaxf(fmaf(sc.x, v.x, sh.x), 0.f);
          v.y = fmaxf(fmaf(sc.y, v.y, sh.y), 0.f);
          v.z = fmaxf(fmaf(sc.z, v.z, sh.z), 0.f);
          v.w = fmaxf(fmaf(sc.w, v.w, sh.w), 0.f);
        }
      }
      sIn[k + 0][r] = v.x;
      sIn[k + 1][r] = v.y;
      sIn[k + 2][r] = v.z;
      sIn[k + 3][r] = v.w;
      const float4 w = *(const float4*)(gw + k);
      sW[k + 0][r] = w.x;
      sW[k + 1][r] = w.y;
      sW[k + 2][r] = w.z;
      sW[k + 3][r] = w.w;
    }
  }
  if (tid < TC) {
    bsum[tid] = 0.f;
    bsq[tid] = 0.f;
  }
  __syncthreads();

  const int rx = tid >> 4;
  const int cx = tid & 15;
  float acc[4][4] = {};
#pragma unroll 8
  for (int k = 0; k < DD; ++k) {
    const float4 a = *(const float4*)&sIn[k][rx * 4];
    const float4 b = *(const float4*)&sW[k][cx * 4];
    acc[0][0] = fmaf(a.x, b.x, acc[0][0]);
    acc[0][1] = fmaf(a.x, b.y, acc[0][1]);
    acc[0][2] = fmaf(a.x, b.z, acc[0][2]);
    acc[0][3] = fmaf(a.x, b.w, acc[0][3]);
    acc[1][0] = fmaf(a.y, b.x, acc[1][0]);
    acc[1][1] = fmaf(a.y, b.y, acc[1][1]);
    acc[1][2] = fmaf(a.y, b.z, acc[1][2]);
    acc[1][3] = fmaf(a.y, b.w, acc[1][3]);
    acc[2][0] = fmaf(a.z, b.x, acc[2][0]);
    acc[2][1] = fmaf(a.z, b.y, acc[2][1]);
    acc[2][2] = fmaf(a.z, b.z, acc[2][2]);
    acc[2][3] = fmaf(a.z, b.w, acc[2][3]);
    acc[3][0] = fmaf(a.w, b.x, acc[3][0]);
    acc[3][1] = fmaf(a.w, b.y, acc[3][1]);
    acc[3][2] = fmaf(a.w, b.z, acc[3][2]);
    acc[3][3] = fmaf(a.w, b.w, acc[3][3]);
  }

  const float4 bv = *(const float4*)(bias + c0 + cx * 4);
  float s0 = 0.f, s1 = 0.f, s2 = 0.f, s3 = 0.f;
  float q0 = 0.f, q1 = 0.f, q2 = 0.f, q3 = 0.f;
#pragma unroll
  for (int i = 0; i < 4; ++i) {
    const int row = row0 + rx * 4 + i;
    if (row < NN) {
      float4 o;
      o.x = acc[i][0] + bv.x;
      o.y = acc[i][1] + bv.y;
      o.z = acc[i][2] + bv.z;
      o.w = acc[i][3] + bv.w;
      *(float4*)(out + (long long)row * DD + c0 + cx * 4) = o;
      s0 += o.x; q0 += o.x * o.x;
      s1 += o.y; q1 += o.y * o.y;
      s2 += o.z; q2 += o.z * o.z;
      s3 += o.w; q3 += o.w * o.w;
    }
  }
  atomicAdd(&bsum[cx * 4 + 0], s0);
  atomicAdd(&bsum[cx * 4 + 1], s1);
  atomicAdd(&bsum[cx * 4 + 2], s2);
  atomicAdd(&bsum[cx * 4 + 3], s3);
  atomicAdd(&bsq[cx * 4 + 0], q0);
  atomicAdd(&bsq[cx * 4 + 1], q1);
  atomicAdd(&bsq[cx * 4 + 2], q2);
  atomicAdd(&bsq[cx * 4 + 3], q3);
  __syncthreads();
  if (tid < TC) {
    atomicAdd(&gsum[c0 + tid], bsum[tid]);
    atomicAdd(&gsumsq[c0 + tid], bsq[tid]);
  }
}

// K6: BN stats -> per-column scale/shift (training mode, biased variance)
__global__ void k_bnstats(const float* __restrict__ sum,
                          const float* __restrict__ sumsq,
                          const float* __restrict__ gamma,
                          const float* __restrict__ beta,
                          float* __restrict__ scale,
                          float* __restrict__ shift) {
  const int c = threadIdx.x;
  const float inv_n = 1.0f / (float)NN;
  const float mean = sum[c] * inv_n;
  const float var = sumsq[c] * inv_n - mean * mean;
  const float sc = gamma[c] * rsqrtf(var + BN_EPS);
  scale[c] = sc;
  shift[c] = beta[c] - mean * sc;
}

// K7: final BN + ReLU elementwise
__global__ __launch_bounds__(256) void k_bnrelu(const float* __restrict__ in,
                                                const float* __restrict__ scale,
                                                const float* __restrict__ shift,
                                                float* __restrict__ out) {
  const int gid = blockIdx.x * 256 + threadIdx.x;
  const int c = (gid & 31) * 4;
  float4 v = ((const float4*)in)[gid];
  const float4 sc = *(const float4*)(scale + c);
  const float4 sh = *(const float4*)(shift + c);
  v.x = fmaxf(fmaf(sc.x, v.x, sh.x), 0.f);
  v.y = fmaxf(fmaf(sc.y, v.y, sh.y), 0.f);
  v.z = fmaxf(fmaf(sc.z, v.z, sh.z), 0.f);
  v.w = fmaxf(fmaf(sc.w, v.w, sh.w), 0.f);
  ((float4*)out)[gid] = v;
}

// ---------------------------------------------------------------------------
extern "C" void kernel_launch(void* const* d_in, const int* in_sizes, int n_in,
                              void* d_out, int out_size, void* d_ws, size_t ws_size,
                              hipStream_t stream) {
  const float* x = (const float*)d_in[0];
  const int* ei = (const int*)d_in[1];  // [2][E]: rows then cols
  const float* eps = (const float*)d_in[2];
  const float* W1 = (const float*)d_in[3];
  const float* b1 = (const float*)d_in[4];
  const float* g1 = (const float*)d_in[5];
  const float* be1 = (const float*)d_in[6];
  const float* W2 = (const float*)d_in[7];
  const float* b2 = (const float*)d_in[8];
  const float* g2 = (const float*)d_in[9];
  const float* be2 = (const float*)d_in[10];
  float* out = (float*)d_out;

  const int* rows = ei;
  const int* cols = ei + EE;

  // int scratch inside d_out (dead until GEMM1 writes d_out)
  int* scr = (int*)d_out;
  int* offs = scr;             // NN+1
  int* cnt = scr + 50008;      // NN
  int* cursor = scr + 100016;  // NN
  int* sc = scr + 150024;      // EE

  float* h0 = (float*)d_ws;             // N*D floats
  float* stats = h0 + (size_t)NN * DD;  // 1024 floats
  float* sum1 = stats + 0;
  float* sumsq1 = stats + 128;
  float* scale1 = stats + 256;
  float* shift1 = stats + 384;
  float* sum2 = stats + 512;
  float* sumsq2 = stats + 640;
  float* scale2 = stats + 768;
  float* shift2 = stats + 896;

  const int ew_blocks = (NN * DD / 4) / 256;  // 6250

  // --- CSR build + gather aggregation ---
  k_zero<<<(NN + 255) / 256, 256, 0, stream>>>(cnt, stats);
  k_hist<<<(EE + 255) / 256, 256, 0, stream>>>(rows, cnt);
  k_scan<<<1, SCAN_T, 0, stream>>>(cnt, offs, cursor);
  k_place<<<(EE + 255) / 256, 256, 0, stream>>>(rows, cols, cursor, sc);
  k_agg<<<NN / 8, 256, 0, stream>>>(x, eps, offs, sc, h0);

  // --- two fused GEMM+BN layers ---
  dim3 gg((NN + TR - 1) / TR, DD / TC);
  k_gemm<<<gg, 256, 0, stream>>>(h0, W1, b1, nullptr, nullptr, out, sum1, sumsq1);
  k_bnstats<<<1, 128, 0, stream>>>(sum1, sumsq1, g1, be1, scale1, shift1);
  k_gemm<<<gg, 256, 0, stream>>>(out, W2, b2, scale1, shift1, h0, sum2, sumsq2);
  k_bnstats<<<1, 128, 0, stream>>>(sum2, sumsq2, g2, be2, scale2, shift2);
  k_bnrelu<<<ew_blocks, 256, 0, stream>>>(h0, scale2, shift2, out);
}

// Round 3
// 381.255 us; speedup vs baseline: 4.1475x; 1.2677x over previous
//
#include <hip/hip_runtime.h>

#define NN 50000
#define EE 800000
#define DD 128
#define BN_EPS 1e-5f
#define TR 64
#define TC 64
#define SCAN_B 196  // ceil(50000/256)

// ---------------------------------------------------------------------------
// Scratch plan:
//   d_out (6.4M floats) doubles as int scratch for the CSR build; it is dead
//   until GEMM1 writes it (stream-ordered after k_agg consumes the scratch).
//     offs     : [0, NN+1)
//     cnt      : [50008, +NN)
//     cursor   : [100016, +NN)
//     sc       : [150024, +EE)    column ids sorted by destination row
//     partial  : [950024, +256)   per-chunk sums -> exclusive bases
//   d_ws: h0 (N*D floats) + stats (1024 floats)
// ---------------------------------------------------------------------------

// K0: zero in-degree counters + BN stat accumulators
__global__ __launch_bounds__(256) void k_zero(int* __restrict__ cnt,
                                              float* __restrict__ stats) {
  const int gid = blockIdx.x * 256 + threadIdx.x;
  if (gid < NN) cnt[gid] = 0;
  if (gid < 1024) stats[gid] = 0.0f;
}

// K1: in-degree histogram (int atomics on L2-resident 200KB array)
__global__ __launch_bounds__(256) void k_hist(const int* __restrict__ rows,
                                              int* __restrict__ cnt) {
  const int e = blockIdx.x * 256 + threadIdx.x;
  if (e < EE) atomicAdd(&cnt[rows[e]], 1);
}

// K2a: per-chunk reduce: partial[b] = sum(cnt[b*256 .. b*256+255])
__global__ __launch_bounds__(256) void k_scanA(const int* __restrict__ cnt,
                                               int* __restrict__ partial) {
  __shared__ int red[256];
  const int t = threadIdx.x;
  const int i = blockIdx.x * 256 + t;
  red[t] = (i < NN) ? cnt[i] : 0;
  __syncthreads();
#pragma unroll
  for (int off = 128; off > 0; off >>= 1) {
    if (t < off) red[t] += red[t + off];
    __syncthreads();
  }
  if (t == 0) partial[blockIdx.x] = red[0];
}

// K2b: exclusive scan of the 196 partials (single tiny block)
__global__ __launch_bounds__(256) void k_scanB(int* __restrict__ partial,
                                               int* __restrict__ offs) {
  __shared__ int s[256];
  const int t = threadIdx.x;
  const int own = (t < SCAN_B) ? partial[t] : 0;
  s[t] = own;
  __syncthreads();
#pragma unroll
  for (int off = 1; off < 256; off <<= 1) {
    const int v = (t >= off) ? s[t - off] : 0;
    __syncthreads();
    s[t] += v;
    __syncthreads();
  }
  if (t < SCAN_B) partial[t] = s[t] - own;  // exclusive base per chunk
  if (t == 0) offs[NN] = EE;
}

// K2c: per-chunk exclusive scan + base -> offs, cursor
__global__ __launch_bounds__(256) void k_scanC(const int* __restrict__ cnt,
                                               const int* __restrict__ partial,
                                               int* __restrict__ offs,
                                               int* __restrict__ cursor) {
  __shared__ int s[256];
  const int t = threadIdx.x;
  const int i = blockIdx.x * 256 + t;
  const int own = (i < NN) ? cnt[i] : 0;
  s[t] = own;
  __syncthreads();
#pragma unroll
  for (int off = 1; off < 256; off <<= 1) {
    const int v = (t >= off) ? s[t - off] : 0;
    __syncthreads();
    s[t] += v;
    __syncthreads();
  }
  if (i < NN) {
    const int o = partial[blockIdx.x] + s[t] - own;
    offs[i] = o;
    cursor[i] = o;
  }
}

// K3: place column ids into destination-sorted order
__global__ __launch_bounds__(256) void k_place(const int* __restrict__ rows,
                                               const int* __restrict__ cols,
                                               int* __restrict__ cursor,
                                               int* __restrict__ sc) {
  const int e = blockIdx.x * 256 + threadIdx.x;
  if (e < EE) {
    const int pos = atomicAdd(&cursor[rows[e]], 1);
    sc[pos] = cols[e];
  }
}

// K4: gather-based aggregation. One 32-lane group per row; lane j owns
// float4 chunk j. h0[v] = (1+eps)*x[v] + sum_{u in N(v)} x[u].
__global__ __launch_bounds__(256) void k_agg(const float* __restrict__ x,
                                             const float* __restrict__ eps,
                                             const int* __restrict__ offs,
                                             const int* __restrict__ sc,
                                             float* __restrict__ h0) {
  const int g = threadIdx.x >> 5;    // 0..7: row group within block
  const int j = threadIdx.x & 31;    // float4 chunk within row
  const int v = blockIdx.x * 8 + g;  // 6250*8 == 50000 exactly
  const int beg = offs[v];
  const int end = offs[v + 1];
  const float s = 1.0f + eps[0];
  float4 acc = ((const float4*)(x + (size_t)v * DD))[j];
  acc.x *= s; acc.y *= s; acc.z *= s; acc.w *= s;
  int i = beg;
  for (; i + 2 <= end; i += 2) {
    const int u0 = sc[i];
    const int u1 = sc[i + 1];
    const float4 a = ((const float4*)(x + (size_t)u0 * DD))[j];
    const float4 b = ((const float4*)(x + (size_t)u1 * DD))[j];
    acc.x += a.x + b.x;
    acc.y += a.y + b.y;
    acc.z += a.z + b.z;
    acc.w += a.w + b.w;
  }
  if (i < end) {
    const int u = sc[i];
    const float4 a = ((const float4*)(x + (size_t)u * DD))[j];
    acc.x += a.x; acc.y += a.y; acc.z += a.z; acc.w += a.w;
  }
  ((float4*)(h0 + (size_t)v * DD))[j] = acc;
}

// ---------------------------------------------------------------------------
// K5: fused GEMM: out[n][c] = sum_k act(in[n][k]) * W[c][k] + bias[c]
//   act = identity, or relu(ascale[k]*v + ashift[k]) when ascale != nullptr
// Also accumulates per-column sum / sumsq of out (for BatchNorm stats).
// ---------------------------------------------------------------------------
__global__ __launch_bounds__(256) void k_gemm(const float* __restrict__ in,
                                              const float* __restrict__ W,
                                              const float* __restrict__ bias,
                                              const float* __restrict__ ascale,
                                              const float* __restrict__ ashift,
                                              float* __restrict__ out,
                                              float* __restrict__ gsum,
                                              float* __restrict__ gsumsq) {
  __shared__ __align__(16) float sIn[DD][TR];
  __shared__ __align__(16) float sW[DD][TC];
  __shared__ float bsum[TC];
  __shared__ float bsq[TC];

  const int tid = threadIdx.x;
  const int row0 = blockIdx.x * TR;
  const int c0 = blockIdx.y * TC;

  {
    const int r = tid & 63;
    const int kc0 = tid >> 6;  // 0..3
    const long long grow = (long long)row0 + r;
    const bool valid = grow < NN;
    const float* gin = in + grow * DD;
    const float* gw = W + (long long)(c0 + r) * DD;
#pragma unroll
    for (int it = 0; it < 8; ++it) {
      const int k = (kc0 + it * 4) * 4;  // 0..124 step 4
      float4 v = make_float4(0.f, 0.f, 0.f, 0.f);
      if (valid) {
        v = *(const float4*)(gin + k);
        if (ascale) {
          const float4 sc = *(const float4*)(ascale + k);
          const float4 sh = *(const float4*)(ashift + k);
          v.x = fmaxf(fmaf(sc.x, v.x, sh.x), 0.f);
          v.y = fmaxf(fmaf(sc.y, v.y, sh.y), 0.f);
          v.z = fmaxf(fmaf(sc.z, v.z, sh.z), 0.f);
          v.w = fmaxf(fmaf(sc.w, v.w, sh.w), 0.f);
        }
      }
      sIn[k + 0][r] = v.x;
      sIn[k + 1][r] = v.y;
      sIn[k + 2][r] = v.z;
      sIn[k + 3][r] = v.w;
      const float4 w = *(const float4*)(gw + k);
      sW[k + 0][r] = w.x;
      sW[k + 1][r] = w.y;
      sW[k + 2][r] = w.z;
      sW[k + 3][r] = w.w;
    }
  }
  if (tid < TC) {
    bsum[tid] = 0.f;
    bsq[tid] = 0.f;
  }
  __syncthreads();

  const int rx = tid >> 4;
  const int cx = tid & 15;
  float acc[4][4] = {};
#pragma unroll 8
  for (int k = 0; k < DD; ++k) {
    const float4 a = *(const float4*)&sIn[k][rx * 4];
    const float4 b = *(const float4*)&sW[k][cx * 4];
    acc[0][0] = fmaf(a.x, b.x, acc[0][0]);
    acc[0][1] = fmaf(a.x, b.y, acc[0][1]);
    acc[0][2] = fmaf(a.x, b.z, acc[0][2]);
    acc[0][3] = fmaf(a.x, b.w, acc[0][3]);
    acc[1][0] = fmaf(a.y, b.x, acc[1][0]);
    acc[1][1] = fmaf(a.y, b.y, acc[1][1]);
    acc[1][2] = fmaf(a.y, b.z, acc[1][2]);
    acc[1][3] = fmaf(a.y, b.w, acc[1][3]);
    acc[2][0] = fmaf(a.z, b.x, acc[2][0]);
    acc[2][1] = fmaf(a.z, b.y, acc[2][1]);
    acc[2][2] = fmaf(a.z, b.z, acc[2][2]);
    acc[2][3] = fmaf(a.z, b.w, acc[2][3]);
    acc[3][0] = fmaf(a.w, b.x, acc[3][0]);
    acc[3][1] = fmaf(a.w, b.y, acc[3][1]);
    acc[3][2] = fmaf(a.w, b.z, acc[3][2]);
    acc[3][3] = fmaf(a.w, b.w, acc[3][3]);
  }

  const float4 bv = *(const float4*)(bias + c0 + cx * 4);
  float s0 = 0.f, s1 = 0.f, s2 = 0.f, s3 = 0.f;
  float q0 = 0.f, q1 = 0.f, q2 = 0.f, q3 = 0.f;
#pragma unroll
  for (int i = 0; i < 4; ++i) {
    const int row = row0 + rx * 4 + i;
    if (row < NN) {
      float4 o;
      o.x = acc[i][0] + bv.x;
      o.y = acc[i][1] + bv.y;
      o.z = acc[i][2] + bv.z;
      o.w = acc[i][3] + bv.w;
      *(float4*)(out + (long long)row * DD + c0 + cx * 4) = o;
      s0 += o.x; q0 += o.x * o.x;
      s1 += o.y; q1 += o.y * o.y;
      s2 += o.z; q2 += o.z * o.z;
      s3 += o.w; q3 += o.w * o.w;
    }
  }
  atomicAdd(&bsum[cx * 4 + 0], s0);
  atomicAdd(&bsum[cx * 4 + 1], s1);
  atomicAdd(&bsum[cx * 4 + 2], s2);
  atomicAdd(&bsum[cx * 4 + 3], s3);
  atomicAdd(&bsq[cx * 4 + 0], q0);
  atomicAdd(&bsq[cx * 4 + 1], q1);
  atomicAdd(&bsq[cx * 4 + 2], q2);
  atomicAdd(&bsq[cx * 4 + 3], q3);
  __syncthreads();
  if (tid < TC) {
    atomicAdd(&gsum[c0 + tid], bsum[tid]);
    atomicAdd(&gsumsq[c0 + tid], bsq[tid]);
  }
}

// K6: BN stats -> per-column scale/shift (training mode, biased variance)
__global__ void k_bnstats(const float* __restrict__ sum,
                          const float* __restrict__ sumsq,
                          const float* __restrict__ gamma,
                          const float* __restrict__ beta,
                          float* __restrict__ scale,
                          float* __restrict__ shift) {
  const int c = threadIdx.x;
  const float inv_n = 1.0f / (float)NN;
  const float mean = sum[c] * inv_n;
  const float var = sumsq[c] * inv_n - mean * mean;
  const float sc = gamma[c] * rsqrtf(var + BN_EPS);
  scale[c] = sc;
  shift[c] = beta[c] - mean * sc;
}

// K7: final BN + ReLU elementwise
__global__ __launch_bounds__(256) void k_bnrelu(const float* __restrict__ in,
                                                const float* __restrict__ scale,
                                                const float* __restrict__ shift,
                                                float* __restrict__ out) {
  const int gid = blockIdx.x * 256 + threadIdx.x;
  const int c = (gid & 31) * 4;
  float4 v = ((const float4*)in)[gid];
  const float4 sc = *(const float4*)(scale + c);
  const float4 sh = *(const float4*)(shift + c);
  v.x = fmaxf(fmaf(sc.x, v.x, sh.x), 0.f);
  v.y = fmaxf(fmaf(sc.y, v.y, sh.y), 0.f);
  v.z = fmaxf(fmaf(sc.z, v.z, sh.z), 0.f);
  v.w = fmaxf(fmaf(sc.w, v.w, sh.w), 0.f);
  ((float4*)out)[gid] = v;
}

// ---------------------------------------------------------------------------
extern "C" void kernel_launch(void* const* d_in, const int* in_sizes, int n_in,
                              void* d_out, int out_size, void* d_ws, size_t ws_size,
                              hipStream_t stream) {
  const float* x = (const float*)d_in[0];
  const int* ei = (const int*)d_in[1];  // [2][E]: rows then cols
  const float* eps = (const float*)d_in[2];
  const float* W1 = (const float*)d_in[3];
  const float* b1 = (const float*)d_in[4];
  const float* g1 = (const float*)d_in[5];
  const float* be1 = (const float*)d_in[6];
  const float* W2 = (const float*)d_in[7];
  const float* b2 = (const float*)d_in[8];
  const float* g2 = (const float*)d_in[9];
  const float* be2 = (const float*)d_in[10];
  float* out = (float*)d_out;

  const int* rows = ei;
  const int* cols = ei + EE;

  // int scratch inside d_out (dead until GEMM1 writes d_out)
  int* scr = (int*)d_out;
  int* offs = scr;               // NN+1
  int* cnt = scr + 50008;        // NN
  int* cursor = scr + 100016;    // NN
  int* sc = scr + 150024;        // EE
  int* partial = scr + 950024;   // 256

  float* h0 = (float*)d_ws;             // N*D floats
  float* stats = h0 + (size_t)NN * DD;  // 1024 floats
  float* sum1 = stats + 0;
  float* sumsq1 = stats + 128;
  float* scale1 = stats + 256;
  float* shift1 = stats + 384;
  float* sum2 = stats + 512;
  float* sumsq2 = stats + 640;
  float* scale2 = stats + 768;
  float* shift2 = stats + 896;

  const int ew_blocks = (NN * DD / 4) / 256;  // 6250

  // --- CSR build + gather aggregation ---
  k_zero<<<(NN + 255) / 256, 256, 0, stream>>>(cnt, stats);
  k_hist<<<(EE + 255) / 256, 256, 0, stream>>>(rows, cnt);
  k_scanA<<<SCAN_B, 256, 0, stream>>>(cnt, partial);
  k_scanB<<<1, 256, 0, stream>>>(partial, offs);
  k_scanC<<<SCAN_B, 256, 0, stream>>>(cnt, partial, offs, cursor);
  k_place<<<(EE + 255) / 256, 256, 0, stream>>>(rows, cols, cursor, sc);
  k_agg<<<NN / 8, 256, 0, stream>>>(x, eps, offs, sc, h0);

  // --- two fused GEMM+BN layers ---
  dim3 gg((NN + TR - 1) / TR, DD / TC);
  k_gemm<<<gg, 256, 0, stream>>>(h0, W1, b1, nullptr, nullptr, out, sum1, sumsq1);
  k_bnstats<<<1, 128, 0, stream>>>(sum1, sumsq1, g1, be1, scale1, shift1);
  k_gemm<<<gg, 256, 0, stream>>>(out, W2, b2, scale1, shift1, h0, sum2, sumsq2);
  k_bnstats<<<1, 128, 0, stream>>>(sum2, sumsq2, g2, be2, scale2, shift2);
  k_bnrelu<<<ew_blocks, 256, 0, stream>>>(h0, scale2, shift2, out);
}

// Round 4
// 334.658 us; speedup vs baseline: 4.7250x; 1.1392x over previous
//
#include <hip/hip_runtime.h>

#define NN 50000
#define EE 800000
#define DD 128
#define BN_EPS 1e-5f
#define SCAN_B 196  // ceil(50000/256)

typedef __attribute__((ext_vector_type(8))) short bf16x8;
typedef __attribute__((ext_vector_type(4))) float f32x4;
typedef __attribute__((ext_vector_type(8))) unsigned short u16x8;

__device__ inline unsigned short f2bf(float f) {  // RNE fp32 -> bf16
  unsigned int u = __float_as_uint(f);
  u = (u + 0x7fffu + ((u >> 16) & 1u)) >> 16;
  return (unsigned short)u;
}
__device__ inline float bf2f(unsigned short b) {
  return __uint_as_float(((unsigned int)b) << 16);
}

// ---------------------------------------------------------------------------
// Scratch plan:
//  d_out (25.6MB) = CSR int scratch until GEMM1 overwrites it with h1 (fp32):
//    offs [0,NN+1) | cnt +50008 | cursor +100016 | sc +150024 | partial +950024
//  d_ws (25.6MB + 4KB):
//    region A [0, 12.8M):  h0_bf16 (k_agg->GEMM1);  later W2_bf16 (32KB)
//    region B [12.8M, 25.6M): W1_bf16 (32KB);       later h2_bf16 (GEMM2 out)
//    stats    [25.6M, +4KB)
// ---------------------------------------------------------------------------

__global__ __launch_bounds__(256) void k_zero(int* __restrict__ cnt,
                                              float* __restrict__ stats) {
  const int gid = blockIdx.x * 256 + threadIdx.x;
  if (gid < NN) cnt[gid] = 0;
  if (gid < 1024) stats[gid] = 0.0f;
}

__global__ __launch_bounds__(256) void k_hist(const int* __restrict__ rows,
                                              int* __restrict__ cnt) {
  const int e = blockIdx.x * 256 + threadIdx.x;
  if (e < EE) atomicAdd(&cnt[rows[e]], 1);
}

__global__ __launch_bounds__(256) void k_scanA(const int* __restrict__ cnt,
                                               int* __restrict__ partial) {
  __shared__ int red[256];
  const int t = threadIdx.x;
  const int i = blockIdx.x * 256 + t;
  red[t] = (i < NN) ? cnt[i] : 0;
  __syncthreads();
#pragma unroll
  for (int off = 128; off > 0; off >>= 1) {
    if (t < off) red[t] += red[t + off];
    __syncthreads();
  }
  if (t == 0) partial[blockIdx.x] = red[0];
}

__global__ __launch_bounds__(256) void k_scanB(int* __restrict__ partial,
                                               int* __restrict__ offs) {
  __shared__ int s[256];
  const int t = threadIdx.x;
  const int own = (t < SCAN_B) ? partial[t] : 0;
  s[t] = own;
  __syncthreads();
#pragma unroll
  for (int off = 1; off < 256; off <<= 1) {
    const int v = (t >= off) ? s[t - off] : 0;
    __syncthreads();
    s[t] += v;
    __syncthreads();
  }
  if (t < SCAN_B) partial[t] = s[t] - own;
  if (t == 0) offs[NN] = EE;
}

__global__ __launch_bounds__(256) void k_scanC(const int* __restrict__ cnt,
                                               const int* __restrict__ partial,
                                               int* __restrict__ offs,
                                               int* __restrict__ cursor) {
  __shared__ int s[256];
  const int t = threadIdx.x;
  const int i = blockIdx.x * 256 + t;
  const int own = (i < NN) ? cnt[i] : 0;
  s[t] = own;
  __syncthreads();
#pragma unroll
  for (int off = 1; off < 256; off <<= 1) {
    const int v = (t >= off) ? s[t - off] : 0;
    __syncthreads();
    s[t] += v;
    __syncthreads();
  }
  if (i < NN) {
    const int o = partial[blockIdx.x] + s[t] - own;
    offs[i] = o;
    cursor[i] = o;
  }
}

__global__ __launch_bounds__(256) void k_place(const int* __restrict__ rows,
                                               const int* __restrict__ cols,
                                               int* __restrict__ cursor,
                                               int* __restrict__ sc) {
  const int e = blockIdx.x * 256 + threadIdx.x;
  if (e < EE) {
    const int pos = atomicAdd(&cursor[rows[e]], 1);
    sc[pos] = cols[e];
  }
}

// fp32 [128][128] -> bf16 (row-major preserved). 16 blocks x 256 x 4 elems.
__global__ __launch_bounds__(256) void k_convW(const float* __restrict__ W,
                                               unsigned short* __restrict__ Wb) {
  const int gid = blockIdx.x * 256 + threadIdx.x;  // over 4096 float4s
  const float4 v = ((const float4*)W)[gid];
  ushort4 o;
  o.x = f2bf(v.x); o.y = f2bf(v.y); o.z = f2bf(v.z); o.w = f2bf(v.w);
  ((ushort4*)Wb)[gid] = o;
}

// K4: gather aggregation -> bf16. One 32-lane group per row.
__global__ __launch_bounds__(256) void k_agg(const float* __restrict__ x,
                                             const float* __restrict__ eps,
                                             const int* __restrict__ offs,
                                             const int* __restrict__ sc,
                                             unsigned short* __restrict__ h0b) {
  const int g = threadIdx.x >> 5;
  const int j = threadIdx.x & 31;
  const int v = blockIdx.x * 8 + g;  // 6250*8 == 50000
  const int beg = offs[v];
  const int end = offs[v + 1];
  const float s = 1.0f + eps[0];
  float4 acc = ((const float4*)(x + (size_t)v * DD))[j];
  acc.x *= s; acc.y *= s; acc.z *= s; acc.w *= s;
  int i = beg;
  for (; i + 2 <= end; i += 2) {
    const int u0 = sc[i];
    const int u1 = sc[i + 1];
    const float4 a = ((const float4*)(x + (size_t)u0 * DD))[j];
    const float4 b = ((const float4*)(x + (size_t)u1 * DD))[j];
    acc.x += a.x + b.x;
    acc.y += a.y + b.y;
    acc.z += a.z + b.z;
    acc.w += a.w + b.w;
  }
  if (i < end) {
    const int u = sc[i];
    const float4 a = ((const float4*)(x + (size_t)u * DD))[j];
    acc.x += a.x; acc.y += a.y; acc.z += a.z; acc.w += a.w;
  }
  ushort4 o;
  o.x = f2bf(acc.x); o.y = f2bf(acc.y); o.z = f2bf(acc.z); o.w = f2bf(acc.w);
  ((ushort4*)(h0b + (size_t)v * DD))[j] = o;
}

// ---------------------------------------------------------------------------
// MFMA GEMM 1: h1[n][c] = sum_k h0b[n][k] * W1b[c][k] + b1[c]   (fp32 out)
// Block = 4 waves; wave handles 16 rows x 128 cols; no LDS tiling:
// A-frag and B-frag are direct 16B bf16 loads (A[m=lane&15][k=quad*8+j]).
// Per-column sum/sumsq accumulated for BN (shuffle + LDS + global atomics).
// ---------------------------------------------------------------------------
__global__ __launch_bounds__(256) void k_gemm1(const unsigned short* __restrict__ A,
                                               const unsigned short* __restrict__ W,
                                               const float* __restrict__ bias,
                                               float* __restrict__ out,
                                               float* __restrict__ gsum,
                                               float* __restrict__ gsumsq) {
  __shared__ float bsum[DD];
  __shared__ float bsq[DD];
  const int tid = threadIdx.x;
  const int wv = tid >> 6;
  const int lane = tid & 63;
  const int quad = lane >> 4;
  const int l16 = lane & 15;
  if (tid < DD) { bsum[tid] = 0.f; bsq[tid] = 0.f; }
  __syncthreads();

  const int rowbase = blockIdx.x * 64 + wv * 16 + l16;
  const int arow = rowbase < NN ? rowbase : NN - 1;  // clamp; stores guarded
  const unsigned short* aptr = A + (size_t)arow * DD + quad * 8;

  f32x4 acc[8];
#pragma unroll
  for (int n = 0; n < 8; ++n) acc[n] = (f32x4){0.f, 0.f, 0.f, 0.f};

#pragma unroll
  for (int kk = 0; kk < 4; ++kk) {
    const bf16x8 af = *(const bf16x8*)(aptr + kk * 32);
#pragma unroll
    for (int n = 0; n < 8; ++n) {
      const bf16x8 bf =
          *(const bf16x8*)(W + (size_t)(n * 16 + l16) * DD + quad * 8 + kk * 32);
      acc[n] = __builtin_amdgcn_mfma_f32_16x16x32_bf16(af, bf, acc[n], 0, 0, 0);
    }
  }

  // epilogue: C/D layout col=lane&15, row=quad*4+reg
  const int orow0 = blockIdx.x * 64 + wv * 16 + quad * 4;
#pragma unroll
  for (int n = 0; n < 8; ++n) {
    const int col = n * 16 + l16;
    const float bv = bias[col];
    float s = 0.f, q = 0.f;
#pragma unroll
    for (int r = 0; r < 4; ++r) {
      const int row = orow0 + r;
      if (row < NN) {
        const float o = acc[n][r] + bv;
        out[(size_t)row * DD + col] = o;
        s += o; q += o * o;
      }
    }
    s += __shfl_xor(s, 16); q += __shfl_xor(q, 16);
    s += __shfl_xor(s, 32); q += __shfl_xor(q, 32);
    if (quad == 0) { atomicAdd(&bsum[col], s); atomicAdd(&bsq[col], q); }
  }
  __syncthreads();
  if (tid < DD) {
    atomicAdd(&gsum[tid], bsum[tid]);
    atomicAdd(&gsumsq[tid], bsq[tid]);
  }
}

// ---------------------------------------------------------------------------
// MFMA GEMM 2: A = relu(scale1*h1+shift1) built inline from fp32 h1;
// out = bf16 h2 (pre-BN2); stats from fp32 acc.
// ---------------------------------------------------------------------------
__global__ __launch_bounds__(256) void k_gemm2(const float* __restrict__ A,
                                               const float* __restrict__ ascale,
                                               const float* __restrict__ ashift,
                                               const unsigned short* __restrict__ W,
                                               const float* __restrict__ bias,
                                               unsigned short* __restrict__ outb,
                                               float* __restrict__ gsum,
                                               float* __restrict__ gsumsq) {
  __shared__ float bsum[DD];
  __shared__ float bsq[DD];
  const int tid = threadIdx.x;
  const int wv = tid >> 6;
  const int lane = tid & 63;
  const int quad = lane >> 4;
  const int l16 = lane & 15;
  if (tid < DD) { bsum[tid] = 0.f; bsq[tid] = 0.f; }
  __syncthreads();

  const int rowbase = blockIdx.x * 64 + wv * 16 + l16;
  const int arow = rowbase < NN ? rowbase : NN - 1;
  const float* aptr = A + (size_t)arow * DD + quad * 8;

  f32x4 acc[8];
#pragma unroll
  for (int n = 0; n < 8; ++n) acc[n] = (f32x4){0.f, 0.f, 0.f, 0.f};

#pragma unroll
  for (int kk = 0; kk < 4; ++kk) {
    const int kbase = kk * 32 + quad * 8;
    const float4 a0 = *(const float4*)(aptr + kk * 32);
    const float4 a1 = *(const float4*)(aptr + kk * 32 + 4);
    const float4 s0 = *(const float4*)(ascale + kbase);
    const float4 s1 = *(const float4*)(ascale + kbase + 4);
    const float4 h0 = *(const float4*)(ashift + kbase);
    const float4 h1 = *(const float4*)(ashift + kbase + 4);
    bf16x8 af;
    af[0] = (short)f2bf(fmaxf(fmaf(s0.x, a0.x, h0.x), 0.f));
    af[1] = (short)f2bf(fmaxf(fmaf(s0.y, a0.y, h0.y), 0.f));
    af[2] = (short)f2bf(fmaxf(fmaf(s0.z, a0.z, h0.z), 0.f));
    af[3] = (short)f2bf(fmaxf(fmaf(s0.w, a0.w, h0.w), 0.f));
    af[4] = (short)f2bf(fmaxf(fmaf(s1.x, a1.x, h1.x), 0.f));
    af[5] = (short)f2bf(fmaxf(fmaf(s1.y, a1.y, h1.y), 0.f));
    af[6] = (short)f2bf(fmaxf(fmaf(s1.z, a1.z, h1.z), 0.f));
    af[7] = (short)f2bf(fmaxf(fmaf(s1.w, a1.w, h1.w), 0.f));
#pragma unroll
    for (int n = 0; n < 8; ++n) {
      const bf16x8 bf =
          *(const bf16x8*)(W + (size_t)(n * 16 + l16) * DD + kbase);
      acc[n] = __builtin_amdgcn_mfma_f32_16x16x32_bf16(af, bf, acc[n], 0, 0, 0);
    }
  }

  const int orow0 = blockIdx.x * 64 + wv * 16 + quad * 4;
#pragma unroll
  for (int n = 0; n < 8; ++n) {
    const int col = n * 16 + l16;
    const float bv = bias[col];
    float s = 0.f, q = 0.f;
#pragma unroll
    for (int r = 0; r < 4; ++r) {
      const int row = orow0 + r;
      if (row < NN) {
        const float o = acc[n][r] + bv;
        outb[(size_t)row * DD + col] = f2bf(o);
        s += o; q += o * o;
      }
    }
    s += __shfl_xor(s, 16); q += __shfl_xor(q, 16);
    s += __shfl_xor(s, 32); q += __shfl_xor(q, 32);
    if (quad == 0) { atomicAdd(&bsum[col], s); atomicAdd(&bsq[col], q); }
  }
  __syncthreads();
  if (tid < DD) {
    atomicAdd(&gsum[tid], bsum[tid]);
    atomicAdd(&gsumsq[tid], bsq[tid]);
  }
}

// BN stats -> per-column scale/shift (training mode, biased variance)
__global__ void k_bnstats(const float* __restrict__ sum,
                          const float* __restrict__ sumsq,
                          const float* __restrict__ gamma,
                          const float* __restrict__ beta,
                          float* __restrict__ scale,
                          float* __restrict__ shift) {
  const int c = threadIdx.x;
  const float inv_n = 1.0f / (float)NN;
  const float mean = sum[c] * inv_n;
  const float var = sumsq[c] * inv_n - mean * mean;
  const float sc = gamma[c] * rsqrtf(var + BN_EPS);
  scale[c] = sc;
  shift[c] = beta[c] - mean * sc;
}

// final BN + ReLU: fp32 out from bf16 h2
__global__ __launch_bounds__(256) void k_bnrelu(const unsigned short* __restrict__ in,
                                                const float* __restrict__ scale,
                                                const float* __restrict__ shift,
                                                float* __restrict__ out) {
  const int gid = blockIdx.x * 256 + threadIdx.x;  // over N*D/8 groups
  const int c = (gid & 15) * 8;
  const u16x8 a = ((const u16x8*)in)[gid];
  const float4 sc0 = *(const float4*)(scale + c);
  const float4 sc1 = *(const float4*)(scale + c + 4);
  const float4 sh0 = *(const float4*)(shift + c);
  const float4 sh1 = *(const float4*)(shift + c + 4);
  float4 o0, o1;
  o0.x = fmaxf(fmaf(sc0.x, bf2f(a[0]), sh0.x), 0.f);
  o0.y = fmaxf(fmaf(sc0.y, bf2f(a[1]), sh0.y), 0.f);
  o0.z = fmaxf(fmaf(sc0.z, bf2f(a[2]), sh0.z), 0.f);
  o0.w = fmaxf(fmaf(sc0.w, bf2f(a[3]), sh0.w), 0.f);
  o1.x = fmaxf(fmaf(sc1.x, bf2f(a[4]), sh1.x), 0.f);
  o1.y = fmaxf(fmaf(sc1.y, bf2f(a[5]), sh1.y), 0.f);
  o1.z = fmaxf(fmaf(sc1.z, bf2f(a[6]), sh1.z), 0.f);
  o1.w = fmaxf(fmaf(sc1.w, bf2f(a[7]), sh1.w), 0.f);
  ((float4*)out)[gid * 2] = o0;
  ((float4*)out)[gid * 2 + 1] = o1;
}

// ---------------------------------------------------------------------------
extern "C" void kernel_launch(void* const* d_in, const int* in_sizes, int n_in,
                              void* d_out, int out_size, void* d_ws, size_t ws_size,
                              hipStream_t stream) {
  const float* x = (const float*)d_in[0];
  const int* ei = (const int*)d_in[1];
  const float* eps = (const float*)d_in[2];
  const float* W1 = (const float*)d_in[3];
  const float* b1 = (const float*)d_in[4];
  const float* g1 = (const float*)d_in[5];
  const float* be1 = (const float*)d_in[6];
  const float* W2 = (const float*)d_in[7];
  const float* b2 = (const float*)d_in[8];
  const float* g2 = (const float*)d_in[9];
  const float* be2 = (const float*)d_in[10];
  float* out = (float*)d_out;

  const int* rows = ei;
  const int* cols = ei + EE;

  // CSR int scratch inside d_out (dead once GEMM1 writes h1 there)
  int* scr = (int*)d_out;
  int* offs = scr;
  int* cnt = scr + 50008;
  int* cursor = scr + 100016;
  int* sc = scr + 150024;
  int* partial = scr + 950024;

  unsigned short* h0b = (unsigned short*)d_ws;            // region A (bf16 N*D)
  unsigned short* regionB = h0b + (size_t)NN * DD;        // region B
  unsigned short* W1b = regionB;                          // 32KB (dies at GEMM2)
  unsigned short* h2b = regionB;                          // bf16 N*D (GEMM2 out)
  unsigned short* W2b = h0b;                              // reuses region A
  float* stats = (float*)(h0b + (size_t)2 * NN * DD);
  float* sum1 = stats + 0;
  float* sumsq1 = stats + 128;
  float* scale1 = stats + 256;
  float* shift1 = stats + 384;
  float* sum2 = stats + 512;
  float* sumsq2 = stats + 640;
  float* scale2 = stats + 768;
  float* shift2 = stats + 896;

  // --- CSR build ---
  k_zero<<<(NN + 255) / 256, 256, 0, stream>>>(cnt, stats);
  k_hist<<<(EE + 255) / 256, 256, 0, stream>>>(rows, cnt);
  k_scanA<<<SCAN_B, 256, 0, stream>>>(cnt, partial);
  k_scanB<<<1, 256, 0, stream>>>(partial, offs);
  k_scanC<<<SCAN_B, 256, 0, stream>>>(cnt, partial, offs, cursor);
  k_place<<<(EE + 255) / 256, 256, 0, stream>>>(rows, cols, cursor, sc);

  // --- aggregate (bf16 out) + weight conversion ---
  k_convW<<<16, 256, 0, stream>>>(W1, W1b);
  k_agg<<<NN / 8, 256, 0, stream>>>(x, eps, offs, sc, h0b);

  // --- layer 1 ---
  const int gblocks = (NN + 63) / 64;  // 782
  k_gemm1<<<gblocks, 256, 0, stream>>>(h0b, W1b, b1, out, sum1, sumsq1);
  k_bnstats<<<1, 128, 0, stream>>>(sum1, sumsq1, g1, be1, scale1, shift1);
  k_convW<<<16, 256, 0, stream>>>(W2, W2b);  // after GEMM1 (reuses region A)

  // --- layer 2 ---
  k_gemm2<<<gblocks, 256, 0, stream>>>(out, scale1, shift1, W2b, b2, h2b,
                                       sum2, sumsq2);
  k_bnstats<<<1, 128, 0, stream>>>(sum2, sumsq2, g2, be2, scale2, shift2);
  k_bnrelu<<<(NN * DD / 8) / 256, 256, 0, stream>>>(h2b, scale2, shift2, out);
}

// Round 5
// 302.836 us; speedup vs baseline: 5.2215x; 1.1051x over previous
//
#include <hip/hip_runtime.h>

#define NN 50000
#define EE 800000
#define DD 128
#define BN_EPS 1e-5f
#define SCAN_B 196   // ceil(50000/256)
#define XCONV_B 3125 // N*D/8/256

typedef __attribute__((ext_vector_type(8))) short bf16x8;
typedef __attribute__((ext_vector_type(4))) float f32x4;
typedef __attribute__((ext_vector_type(8))) unsigned short u16x8;

__device__ inline unsigned short f2bf(float f) {  // RNE fp32 -> bf16
  unsigned int u = __float_as_uint(f);
  u = (u + 0x7fffu + ((u >> 16) & 1u)) >> 16;
  return (unsigned short)u;
}
__device__ inline float bf2f(unsigned short b) {
  return __uint_as_float(((unsigned int)b) << 16);
}

// ---------------------------------------------------------------------------
// Memory plan (all offsets in bytes):
//  d_out (25.6MB):
//    [0, 3.81M)      CSR scratch: offs | cnt +50008i | cursor +100016i |
//                    sc +150024i | partial +950024i
//    [4.0M, 16.8M)   xb  = bf16(x)            (dies after k_agg)
//    [20.0M, +32KB)  W1b = bf16(W1)           (dies after GEMM1)
//    [20.2M, +32KB)  W2b = bf16(W2)           (dies after GEMM2)
//    GEMM1/GEMM2 do NOT write d_out; only k_bnrelu overwrites it at the end.
//  d_ws (25.6MB + 4KB):
//    region A [0, 12.8M):    h0b (k_agg out)  -> h2b (GEMM2 out)
//    region B [12.8M, 25.6M): h1b (GEMM1 out, bf16)
//    stats    [25.6M): sum1 | sumsq1 +128 | sum2 +256 | sumsq2 +384
// 9 dispatches total (was 15).
// ---------------------------------------------------------------------------

// K0: fused prep — x->bf16, W1->bf16, W2->bf16, zero cnt + stats
__global__ __launch_bounds__(256) void k_prep(const float* __restrict__ x,
                                              const float* __restrict__ W1,
                                              const float* __restrict__ W2,
                                              unsigned short* __restrict__ xb,
                                              unsigned short* __restrict__ W1b,
                                              unsigned short* __restrict__ W2b,
                                              int* __restrict__ cnt,
                                              float* __restrict__ stats) {
  const int b = blockIdx.x;
  const int t = threadIdx.x;
  if (b < XCONV_B) {
    const int gid = b * 256 + t;  // 0..799999, 8 floats each
    const float4 v0 = ((const float4*)x)[gid * 2];
    const float4 v1 = ((const float4*)x)[gid * 2 + 1];
    ushort4 o0, o1;
    o0.x = f2bf(v0.x); o0.y = f2bf(v0.y); o0.z = f2bf(v0.z); o0.w = f2bf(v0.w);
    o1.x = f2bf(v1.x); o1.y = f2bf(v1.y); o1.z = f2bf(v1.z); o1.w = f2bf(v1.w);
    ((ushort4*)xb)[gid * 2] = o0;
    ((ushort4*)xb)[gid * 2 + 1] = o1;
    if (gid < NN) cnt[gid] = 0;
    if (gid < 512) stats[gid] = 0.0f;
  } else if (b < XCONV_B + 16) {
    const int gid = (b - XCONV_B) * 256 + t;  // 0..4095 float4s
    const float4 v = ((const float4*)W1)[gid];
    ushort4 o;
    o.x = f2bf(v.x); o.y = f2bf(v.y); o.z = f2bf(v.z); o.w = f2bf(v.w);
    ((ushort4*)W1b)[gid] = o;
  } else {
    const int gid = (b - XCONV_B - 16) * 256 + t;
    const float4 v = ((const float4*)W2)[gid];
    ushort4 o;
    o.x = f2bf(v.x); o.y = f2bf(v.y); o.z = f2bf(v.z); o.w = f2bf(v.w);
    ((ushort4*)W2b)[gid] = o;
  }
}

// K1: in-degree histogram
__global__ __launch_bounds__(256) void k_hist(const int* __restrict__ rows,
                                              int* __restrict__ cnt) {
  const int e = blockIdx.x * 256 + threadIdx.x;
  if (e < EE) atomicAdd(&cnt[rows[e]], 1);
}

// K2a: per-chunk reduce: partial[b] = sum(cnt[b*256 .. b*256+255])
__global__ __launch_bounds__(256) void k_scanA(const int* __restrict__ cnt,
                                               int* __restrict__ partial) {
  __shared__ int red[256];
  const int t = threadIdx.x;
  const int i = blockIdx.x * 256 + t;
  red[t] = (i < NN) ? cnt[i] : 0;
  __syncthreads();
#pragma unroll
  for (int off = 128; off > 0; off >>= 1) {
    if (t < off) red[t] += red[t + off];
    __syncthreads();
  }
  if (t == 0) partial[blockIdx.x] = red[0];
}

// K2b: per-chunk scan with in-block base reduction (scanB folded in)
__global__ __launch_bounds__(256) void k_scanC(const int* __restrict__ cnt,
                                               const int* __restrict__ partial,
                                               int* __restrict__ offs,
                                               int* __restrict__ cursor) {
  __shared__ int s[256];
  __shared__ int base_s;
  const int t = threadIdx.x;
  const int b = blockIdx.x;
  // base = sum of partial[0..b-1]
  s[t] = (t < SCAN_B && t < b) ? partial[t] : 0;
  __syncthreads();
#pragma unroll
  for (int off = 128; off > 0; off >>= 1) {
    if (t < off) s[t] += s[t + off];
    __syncthreads();
  }
  if (t == 0) base_s = s[0];
  __syncthreads();
  const int base = base_s;
  __syncthreads();
  // per-chunk exclusive scan
  const int i = b * 256 + t;
  const int own = (i < NN) ? cnt[i] : 0;
  s[t] = own;
  __syncthreads();
#pragma unroll
  for (int off = 1; off < 256; off <<= 1) {
    const int v = (t >= off) ? s[t - off] : 0;
    __syncthreads();
    s[t] += v;
    __syncthreads();
  }
  if (i < NN) {
    const int o = base + s[t] - own;
    offs[i] = o;
    cursor[i] = o;
  }
  if (b == 0 && t == 0) offs[NN] = EE;
}

// K3: place column ids into destination-sorted order
__global__ __launch_bounds__(256) void k_place(const int* __restrict__ rows,
                                               const int* __restrict__ cols,
                                               int* __restrict__ cursor,
                                               int* __restrict__ sc) {
  const int e = blockIdx.x * 256 + threadIdx.x;
  if (e < EE) {
    const int pos = atomicAdd(&cursor[rows[e]], 1);
    sc[pos] = cols[e];
  }
}

// K4: bf16 gather aggregation. One 64-lane wave per dest row:
// 4 neighbor-slots x 16 lanes; lane owns a 16B chunk; shuffle-reduce slots.
__global__ __launch_bounds__(256) void k_agg(const unsigned short* __restrict__ xb,
                                             const float* __restrict__ eps,
                                             const int* __restrict__ offs,
                                             const int* __restrict__ sc,
                                             unsigned short* __restrict__ h0b) {
  const int wv = threadIdx.x >> 6;
  const int lane = threadIdx.x & 63;
  const int sub = lane >> 4;
  const int l16 = lane & 15;
  const int v = blockIdx.x * 4 + wv;  // 12500*4 == 50000
  const int beg = offs[v];
  const int end = offs[v + 1];

  float acc[8];
  if (sub == 0) {
    const float s = 1.0f + eps[0];
    const u16x8 a = *(const u16x8*)(xb + (size_t)v * DD + l16 * 8);
#pragma unroll
    for (int j = 0; j < 8; ++j) acc[j] = s * bf2f(a[j]);
  } else {
#pragma unroll
    for (int j = 0; j < 8; ++j) acc[j] = 0.f;
  }

  int i = beg + sub;
  for (; i + 4 < end; i += 8) {  // unroll 2: both gathers in flight
    const int u0 = sc[i];
    const int u1 = sc[i + 4];
    const u16x8 a = *(const u16x8*)(xb + (size_t)u0 * DD + l16 * 8);
    const u16x8 b = *(const u16x8*)(xb + (size_t)u1 * DD + l16 * 8);
#pragma unroll
    for (int j = 0; j < 8; ++j) acc[j] += bf2f(a[j]) + bf2f(b[j]);
  }
  if (i < end) {
    const int u = sc[i];
    const u16x8 a = *(const u16x8*)(xb + (size_t)u * DD + l16 * 8);
#pragma unroll
    for (int j = 0; j < 8; ++j) acc[j] += bf2f(a[j]);
  }

#pragma unroll
  for (int j = 0; j < 8; ++j) {
    acc[j] += __shfl_xor(acc[j], 16);
    acc[j] += __shfl_xor(acc[j], 32);
  }
  if (sub == 0) {
    u16x8 o;
#pragma unroll
    for (int j = 0; j < 8; ++j) o[j] = f2bf(acc[j]);
    *(u16x8*)(h0b + (size_t)v * DD + l16 * 8) = o;
  }
}

// ---------------------------------------------------------------------------
// GEMM1: h1b[n][c] = bf16( sum_k h0b[n][k]*W1b[c][k] + b1[c] ); BN1 stats.
// ---------------------------------------------------------------------------
__global__ __launch_bounds__(256) void k_gemm1(const unsigned short* __restrict__ A,
                                               const unsigned short* __restrict__ W,
                                               const float* __restrict__ bias,
                                               unsigned short* __restrict__ outb,
                                               float* __restrict__ gsum,
                                               float* __restrict__ gsumsq) {
  __shared__ float bsum[DD];
  __shared__ float bsq[DD];
  const int tid = threadIdx.x;
  const int wv = tid >> 6;
  const int lane = tid & 63;
  const int quad = lane >> 4;
  const int l16 = lane & 15;
  if (tid < DD) { bsum[tid] = 0.f; bsq[tid] = 0.f; }
  __syncthreads();

  const int rowbase = blockIdx.x * 64 + wv * 16 + l16;
  const int arow = rowbase < NN ? rowbase : NN - 1;  // clamp; stores guarded
  const unsigned short* aptr = A + (size_t)arow * DD + quad * 8;

  f32x4 acc[8];
#pragma unroll
  for (int n = 0; n < 8; ++n) acc[n] = (f32x4){0.f, 0.f, 0.f, 0.f};

#pragma unroll
  for (int kk = 0; kk < 4; ++kk) {
    const bf16x8 af = *(const bf16x8*)(aptr + kk * 32);
#pragma unroll
    for (int n = 0; n < 8; ++n) {
      const bf16x8 bf =
          *(const bf16x8*)(W + (size_t)(n * 16 + l16) * DD + quad * 8 + kk * 32);
      acc[n] = __builtin_amdgcn_mfma_f32_16x16x32_bf16(af, bf, acc[n], 0, 0, 0);
    }
  }

  const int orow0 = blockIdx.x * 64 + wv * 16 + quad * 4;
#pragma unroll
  for (int n = 0; n < 8; ++n) {
    const int col = n * 16 + l16;
    const float bv = bias[col];
    float s = 0.f, q = 0.f;
#pragma unroll
    for (int r = 0; r < 4; ++r) {
      const int row = orow0 + r;
      if (row < NN) {
        const float o = acc[n][r] + bv;
        outb[(size_t)row * DD + col] = f2bf(o);
        s += o; q += o * o;
      }
    }
    s += __shfl_xor(s, 16); q += __shfl_xor(q, 16);
    s += __shfl_xor(s, 32); q += __shfl_xor(q, 32);
    if (quad == 0) { atomicAdd(&bsum[col], s); atomicAdd(&bsq[col], q); }
  }
  __syncthreads();
  if (tid < DD) {
    atomicAdd(&gsum[tid], bsum[tid]);
    atomicAdd(&gsumsq[tid], bsq[tid]);
  }
}

// ---------------------------------------------------------------------------
// GEMM2: BN1 scale/shift computed in-block from sums; A = relu(BN1(h1b)) on
// the fly; out = h2b bf16 (pre-BN2); BN2 stats from fp32 acc.
// ---------------------------------------------------------------------------
__global__ __launch_bounds__(256) void k_gemm2(const unsigned short* __restrict__ A,
                                               const float* __restrict__ sum1,
                                               const float* __restrict__ sumsq1,
                                               const float* __restrict__ gamma,
                                               const float* __restrict__ beta,
                                               const unsigned short* __restrict__ W,
                                               const float* __restrict__ bias,
                                               unsigned short* __restrict__ outb,
                                               float* __restrict__ gsum,
                                               float* __restrict__ gsumsq) {
  __shared__ float lsc[DD];
  __shared__ float lsh[DD];
  __shared__ float bsum[DD];
  __shared__ float bsq[DD];
  const int tid = threadIdx.x;
  const int wv = tid >> 6;
  const int lane = tid & 63;
  const int quad = lane >> 4;
  const int l16 = lane & 15;
  if (tid < DD) {
    const float inv_n = 1.0f / (float)NN;
    const float mean = sum1[tid] * inv_n;
    const float var = sumsq1[tid] * inv_n - mean * mean;
    const float s = gamma[tid] * rsqrtf(var + BN_EPS);
    lsc[tid] = s;
    lsh[tid] = beta[tid] - mean * s;
    bsum[tid] = 0.f;
    bsq[tid] = 0.f;
  }
  __syncthreads();

  const int rowbase = blockIdx.x * 64 + wv * 16 + l16;
  const int arow = rowbase < NN ? rowbase : NN - 1;
  const unsigned short* aptr = A + (size_t)arow * DD + quad * 8;

  f32x4 acc[8];
#pragma unroll
  for (int n = 0; n < 8; ++n) acc[n] = (f32x4){0.f, 0.f, 0.f, 0.f};

#pragma unroll
  for (int kk = 0; kk < 4; ++kk) {
    const int kbase = kk * 32 + quad * 8;
    const u16x8 a = *(const u16x8*)(aptr + kk * 32);
    const float4 s0 = *(const float4*)&lsc[kbase];
    const float4 s1 = *(const float4*)&lsc[kbase + 4];
    const float4 h0 = *(const float4*)&lsh[kbase];
    const float4 h1 = *(const float4*)&lsh[kbase + 4];
    bf16x8 af;
    af[0] = (short)f2bf(fmaxf(fmaf(s0.x, bf2f(a[0]), h0.x), 0.f));
    af[1] = (short)f2bf(fmaxf(fmaf(s0.y, bf2f(a[1]), h0.y), 0.f));
    af[2] = (short)f2bf(fmaxf(fmaf(s0.z, bf2f(a[2]), h0.z), 0.f));
    af[3] = (short)f2bf(fmaxf(fmaf(s0.w, bf2f(a[3]), h0.w), 0.f));
    af[4] = (short)f2bf(fmaxf(fmaf(s1.x, bf2f(a[4]), h1.x), 0.f));
    af[5] = (short)f2bf(fmaxf(fmaf(s1.y, bf2f(a[5]), h1.y), 0.f));
    af[6] = (short)f2bf(fmaxf(fmaf(s1.z, bf2f(a[6]), h1.z), 0.f));
    af[7] = (short)f2bf(fmaxf(fmaf(s1.w, bf2f(a[7]), h1.w), 0.f));
#pragma unroll
    for (int n = 0; n < 8; ++n) {
      const bf16x8 bf =
          *(const bf16x8*)(W + (size_t)(n * 16 + l16) * DD + kbase);
      acc[n] = __builtin_amdgcn_mfma_f32_16x16x32_bf16(af, bf, acc[n], 0, 0, 0);
    }
  }

  const int orow0 = blockIdx.x * 64 + wv * 16 + quad * 4;
#pragma unroll
  for (int n = 0; n < 8; ++n) {
    const int col = n * 16 + l16;
    const float bv = bias[col];
    float s = 0.f, q = 0.f;
#pragma unroll
    for (int r = 0; r < 4; ++r) {
      const int row = orow0 + r;
      if (row < NN) {
        const float o = acc[n][r] + bv;
        outb[(size_t)row * DD + col] = f2bf(o);
        s += o; q += o * o;
      }
    }
    s += __shfl_xor(s, 16); q += __shfl_xor(q, 16);
    s += __shfl_xor(s, 32); q += __shfl_xor(q, 32);
    if (quad == 0) { atomicAdd(&bsum[col], s); atomicAdd(&bsq[col], q); }
  }
  __syncthreads();
  if (tid < DD) {
    atomicAdd(&gsum[tid], bsum[tid]);
    atomicAdd(&gsumsq[tid], bsq[tid]);
  }
}

// K7: final BN2 + ReLU; scale/shift computed in-block from sums.
__global__ __launch_bounds__(256) void k_bnrelu(const unsigned short* __restrict__ in,
                                                const float* __restrict__ sum2,
                                                const float* __restrict__ sumsq2,
                                                const float* __restrict__ gamma,
                                                const float* __restrict__ beta,
                                                float* __restrict__ out) {
  __shared__ float lsc[DD];
  __shared__ float lsh[DD];
  const int t = threadIdx.x;
  if (t < DD) {
    const float inv_n = 1.0f / (float)NN;
    const float mean = sum2[t] * inv_n;
    const float var = sumsq2[t] * inv_n - mean * mean;
    const float s = gamma[t] * rsqrtf(var + BN_EPS);
    lsc[t] = s;
    lsh[t] = beta[t] - mean * s;
  }
  __syncthreads();
  const int gid = blockIdx.x * 256 + t;  // over N*D/8 chunks
  const int c = (gid & 15) * 8;
  const u16x8 a = ((const u16x8*)in)[gid];
  const float4 sc0 = *(const float4*)&lsc[c];
  const float4 sc1 = *(const float4*)&lsc[c + 4];
  const float4 sh0 = *(const float4*)&lsh[c];
  const float4 sh1 = *(const float4*)&lsh[c + 4];
  float4 o0, o1;
  o0.x = fmaxf(fmaf(sc0.x, bf2f(a[0]), sh0.x), 0.f);
  o0.y = fmaxf(fmaf(sc0.y, bf2f(a[1]), sh0.y), 0.f);
  o0.z = fmaxf(fmaf(sc0.z, bf2f(a[2]), sh0.z), 0.f);
  o0.w = fmaxf(fmaf(sc0.w, bf2f(a[3]), sh0.w), 0.f);
  o1.x = fmaxf(fmaf(sc1.x, bf2f(a[4]), sh1.x), 0.f);
  o1.y = fmaxf(fmaf(sc1.y, bf2f(a[5]), sh1.y), 0.f);
  o1.z = fmaxf(fmaf(sc1.z, bf2f(a[6]), sh1.z), 0.f);
  o1.w = fmaxf(fmaf(sc1.w, bf2f(a[7]), sh1.w), 0.f);
  ((float4*)out)[gid * 2] = o0;
  ((float4*)out)[gid * 2 + 1] = o1;
}

// ---------------------------------------------------------------------------
extern "C" void kernel_launch(void* const* d_in, const int* in_sizes, int n_in,
                              void* d_out, int out_size, void* d_ws, size_t ws_size,
                              hipStream_t stream) {
  const float* x = (const float*)d_in[0];
  const int* ei = (const int*)d_in[1];
  const float* eps = (const float*)d_in[2];
  const float* W1 = (const float*)d_in[3];
  const float* b1 = (const float*)d_in[4];
  const float* g1 = (const float*)d_in[5];
  const float* be1 = (const float*)d_in[6];
  const float* W2 = (const float*)d_in[7];
  const float* b2 = (const float*)d_in[8];
  const float* g2 = (const float*)d_in[9];
  const float* be2 = (const float*)d_in[10];
  float* out = (float*)d_out;

  const int* rows = ei;
  const int* cols = ei + EE;

  // d_out scratch (all dead before k_bnrelu writes d_out)
  int* scr = (int*)d_out;
  int* offs = scr;                 // NN+1
  int* cnt = scr + 50008;          // NN
  int* cursor = scr + 100016;      // NN
  int* sc = scr + 150024;          // EE
  int* partial = scr + 950024;     // 196
  unsigned short* xb = (unsigned short*)d_out + 2000000;    // byte 4.0M, 12.8MB
  unsigned short* W1b = (unsigned short*)d_out + 10000000;  // byte 20.0M, 32KB
  unsigned short* W2b = (unsigned short*)d_out + 10100000;  // byte 20.2M, 32KB

  unsigned short* h0b = (unsigned short*)d_ws;        // region A
  unsigned short* h1b = h0b + (size_t)NN * DD;        // region B
  unsigned short* h2b = h0b;                          // region A (reuse)
  float* stats = (float*)(h0b + (size_t)2 * NN * DD);
  float* sum1 = stats + 0;
  float* sumsq1 = stats + 128;
  float* sum2 = stats + 256;
  float* sumsq2 = stats + 384;

  // 1. fused prep: x/W1/W2 -> bf16, zero cnt+stats
  k_prep<<<XCONV_B + 32, 256, 0, stream>>>(x, W1, W2, xb, W1b, W2b, cnt, stats);
  // 2-5. CSR build
  k_hist<<<EE / 256, 256, 0, stream>>>(rows, cnt);
  k_scanA<<<SCAN_B, 256, 0, stream>>>(cnt, partial);
  k_scanC<<<SCAN_B, 256, 0, stream>>>(cnt, partial, offs, cursor);
  k_place<<<EE / 256, 256, 0, stream>>>(rows, cols, cursor, sc);
  // 6. gather aggregation (bf16)
  k_agg<<<NN / 4, 256, 0, stream>>>(xb, eps, offs, sc, h0b);
  // 7-8. fused GEMM+BN layers
  const int gblocks = (NN + 63) / 64;  // 782
  k_gemm1<<<gblocks, 256, 0, stream>>>(h0b, W1b, b1, h1b, sum1, sumsq1);
  k_gemm2<<<gblocks, 256, 0, stream>>>(h1b, sum1, sumsq1, g1, be1, W2b, b2, h2b,
                                       sum2, sumsq2);
  // 9. final BN2+ReLU -> fp32 out
  k_bnrelu<<<(NN * DD / 8) / 256, 256, 0, stream>>>(h2b, sum2, sumsq2, g2, be2, out);
}

// Round 6
// 288.488 us; speedup vs baseline: 5.4812x; 1.0497x over previous
//
#include <hip/hip_runtime.h>

#define NN 50000
#define EE 800000
#define DD 128
#define BN_EPS 1e-5f
#define SCAN_B 196   // ceil(50000/256)
#define XCONV_B 3125 // N*D/8/256
#define BIN_BLOCKS 200
#define BIN_EDGES 4000  // per block; 200*4000 == EE

typedef __attribute__((ext_vector_type(8))) short bf16x8;
typedef __attribute__((ext_vector_type(4))) float f32x4;
typedef __attribute__((ext_vector_type(8))) unsigned short u16x8;

__device__ inline unsigned short f2bf(float f) {  // RNE fp32 -> bf16
  unsigned int u = __float_as_uint(f);
  u = (u + 0x7fffu + ((u >> 16) & 1u)) >> 16;
  return (unsigned short)u;
}
__device__ inline float bf2f(unsigned short b) {
  return __uint_as_float(((unsigned int)b) << 16);
}

// ---------------------------------------------------------------------------
// Memory plan (byte offsets into d_out, 25.6MB):
//   [0, 3.81M)      int scratch: offs | cnt +50008i | cursor +100016i |
//                   sc +150024i | partial +950024i | bcur +950240i
//   [4.0M, 16.8M)   xb  = bf16(x)          (dies after k_agg)
//   [16.8M, 23.2M)  pairs = int2[EE]       (k_bin out, dies after k_place2)
//   [23.28M,+32KB)  W1b; [23.36M,+32KB) W2b
//   d_out is only overwritten (as fp32 out) by the final k_bnrelu.
// d_ws (25.6MB + 4KB): region A h0b->h2b | region B h1b | stats at +25.6M
// 10 dispatches.
// ---------------------------------------------------------------------------

// K0: fused prep — x->bf16, W1->bf16, W2->bf16, zero cnt + stats
__global__ __launch_bounds__(256) void k_prep(const float* __restrict__ x,
                                              const float* __restrict__ W1,
                                              const float* __restrict__ W2,
                                              unsigned short* __restrict__ xb,
                                              unsigned short* __restrict__ W1b,
                                              unsigned short* __restrict__ W2b,
                                              int* __restrict__ cnt,
                                              float* __restrict__ stats) {
  const int b = blockIdx.x;
  const int t = threadIdx.x;
  if (b < XCONV_B) {
    const int gid = b * 256 + t;
    const float4 v0 = ((const float4*)x)[gid * 2];
    const float4 v1 = ((const float4*)x)[gid * 2 + 1];
    ushort4 o0, o1;
    o0.x = f2bf(v0.x); o0.y = f2bf(v0.y); o0.z = f2bf(v0.z); o0.w = f2bf(v0.w);
    o1.x = f2bf(v1.x); o1.y = f2bf(v1.y); o1.z = f2bf(v1.z); o1.w = f2bf(v1.w);
    ((ushort4*)xb)[gid * 2] = o0;
    ((ushort4*)xb)[gid * 2 + 1] = o1;
    if (gid < NN) cnt[gid] = 0;
    if (gid < 512) stats[gid] = 0.0f;
  } else if (b < XCONV_B + 16) {
    const int gid = (b - XCONV_B) * 256 + t;
    const float4 v = ((const float4*)W1)[gid];
    ushort4 o;
    o.x = f2bf(v.x); o.y = f2bf(v.y); o.z = f2bf(v.z); o.w = f2bf(v.w);
    ((ushort4*)W1b)[gid] = o;
  } else {
    const int gid = (b - XCONV_B - 16) * 256 + t;
    const float4 v = ((const float4*)W2)[gid];
    ushort4 o;
    o.x = f2bf(v.x); o.y = f2bf(v.y); o.z = f2bf(v.z); o.w = f2bf(v.w);
    ((ushort4*)W2b)[gid] = o;
  }
}

// K1: in-degree histogram
__global__ __launch_bounds__(256) void k_hist(const int* __restrict__ rows,
                                              int* __restrict__ cnt) {
  const int e = blockIdx.x * 256 + threadIdx.x;
  if (e < EE) atomicAdd(&cnt[rows[e]], 1);
}

// K2a: per-chunk reduce: partial[b] = sum(cnt[b*256 .. b*256+255])
__global__ __launch_bounds__(256) void k_scanA(const int* __restrict__ cnt,
                                               int* __restrict__ partial) {
  __shared__ int red[256];
  const int t = threadIdx.x;
  const int i = blockIdx.x * 256 + t;
  red[t] = (i < NN) ? cnt[i] : 0;
  __syncthreads();
#pragma unroll
  for (int off = 128; off > 0; off >>= 1) {
    if (t < off) red[t] += red[t + off];
    __syncthreads();
  }
  if (t == 0) partial[blockIdx.x] = red[0];
}

// K2b: per-chunk scan; also exports bucket base (bcur) for k_bin.
__global__ __launch_bounds__(256) void k_scanC(const int* __restrict__ cnt,
                                               const int* __restrict__ partial,
                                               int* __restrict__ offs,
                                               int* __restrict__ cursor,
                                               int* __restrict__ bcur) {
  __shared__ int s[256];
  __shared__ int base_s;
  const int t = threadIdx.x;
  const int b = blockIdx.x;
  s[t] = (t < SCAN_B && t < b) ? partial[t] : 0;
  __syncthreads();
#pragma unroll
  for (int off = 128; off > 0; off >>= 1) {
    if (t < off) s[t] += s[t + off];
    __syncthreads();
  }
  if (t == 0) base_s = s[0];
  __syncthreads();
  const int base = base_s;
  __syncthreads();
  const int i = b * 256 + t;
  const int own = (i < NN) ? cnt[i] : 0;
  s[t] = own;
  __syncthreads();
#pragma unroll
  for (int off = 1; off < 256; off <<= 1) {
    const int v = (t >= off) ? s[t - off] : 0;
    __syncthreads();
    s[t] += v;
    __syncthreads();
  }
  if (i < NN) {
    const int o = base + s[t] - own;
    offs[i] = o;
    cursor[i] = o;
  }
  if (t == 0) bcur[b] = base;  // bucket b == rows [b*256,(b+1)*256)
  if (b == 0 && t == 0) offs[NN] = EE;
}

// K3a: bin edges into bucket-contiguous (row,col) pairs.
// Per block: LDS histogram over buckets -> one global range reservation per
// bucket -> direct pair writes into block-private contiguous segments.
__global__ __launch_bounds__(256) void k_bin(const int* __restrict__ rows,
                                             const int* __restrict__ cols,
                                             int* __restrict__ bcur,
                                             int2* __restrict__ pairs) {
  __shared__ int hist[256];
  __shared__ int lbase[256];
  const int t = threadIdx.x;
  const int e0 = blockIdx.x * BIN_EDGES;
  hist[t] = 0;
  __syncthreads();
  int er[16], ec[16];
#pragma unroll
  for (int i = 0; i < 16; ++i) {
    const int idx = t + i * 256;
    if (idx < BIN_EDGES) {
      er[i] = rows[e0 + idx];
      ec[i] = cols[e0 + idx];
      atomicAdd(&hist[er[i] >> 8], 1);
    }
  }
  __syncthreads();
  const int c = hist[t];
  __syncthreads();
  if (c > 0) lbase[t] = atomicAdd(&bcur[t], c);
  hist[t] = 0;  // reuse as local placement cursor
  __syncthreads();
#pragma unroll
  for (int i = 0; i < 16; ++i) {
    const int idx = t + i * 256;
    if (idx < BIN_EDGES) {
      const int bk = er[i] >> 8;
      const int lp = atomicAdd(&hist[bk], 1);
      pairs[lbase[bk] + lp] = make_int2(er[i], ec[i]);
    }
  }
}

// K3b: final placement from bucket-ordered pairs; sc writes now land in a
// ~16KB window per bucket -> L2 absorbs, HBM write ~= |sc|.
__global__ __launch_bounds__(256) void k_place2(const int2* __restrict__ pairs,
                                                int* __restrict__ cursor,
                                                int* __restrict__ sc) {
  const int i = blockIdx.x * 256 + threadIdx.x;  // EE/256 == 3125 blocks
  const int2 p = pairs[i];
  const int pos = atomicAdd(&cursor[p.x], 1);
  sc[pos] = p.y;
}

// K4: bf16 gather aggregation. One 64-lane wave per dest row.
__global__ __launch_bounds__(256) void k_agg(const unsigned short* __restrict__ xb,
                                             const float* __restrict__ eps,
                                             const int* __restrict__ offs,
                                             const int* __restrict__ sc,
                                             unsigned short* __restrict__ h0b) {
  const int wv = threadIdx.x >> 6;
  const int lane = threadIdx.x & 63;
  const int sub = lane >> 4;
  const int l16 = lane & 15;
  const int v = blockIdx.x * 4 + wv;  // 12500*4 == 50000
  const int beg = offs[v];
  const int end = offs[v + 1];

  float acc[8];
  if (sub == 0) {
    const float s = 1.0f + eps[0];
    const u16x8 a = *(const u16x8*)(xb + (size_t)v * DD + l16 * 8);
#pragma unroll
    for (int j = 0; j < 8; ++j) acc[j] = s * bf2f(a[j]);
  } else {
#pragma unroll
    for (int j = 0; j < 8; ++j) acc[j] = 0.f;
  }

  int i = beg + sub;
  for (; i + 4 < end; i += 8) {
    const int u0 = sc[i];
    const int u1 = sc[i + 4];
    const u16x8 a = *(const u16x8*)(xb + (size_t)u0 * DD + l16 * 8);
    const u16x8 b = *(const u16x8*)(xb + (size_t)u1 * DD + l16 * 8);
#pragma unroll
    for (int j = 0; j < 8; ++j) acc[j] += bf2f(a[j]) + bf2f(b[j]);
  }
  if (i < end) {
    const int u = sc[i];
    const u16x8 a = *(const u16x8*)(xb + (size_t)u * DD + l16 * 8);
#pragma unroll
    for (int j = 0; j < 8; ++j) acc[j] += bf2f(a[j]);
  }

#pragma unroll
  for (int j = 0; j < 8; ++j) {
    acc[j] += __shfl_xor(acc[j], 16);
    acc[j] += __shfl_xor(acc[j], 32);
  }
  if (sub == 0) {
    u16x8 o;
#pragma unroll
    for (int j = 0; j < 8; ++j) o[j] = f2bf(acc[j]);
    *(u16x8*)(h0b + (size_t)v * DD + l16 * 8) = o;
  }
}

// ---------------------------------------------------------------------------
// GEMM1: h1b[n][c] = bf16( sum_k h0b[n][k]*W1b[c][k] + b1[c] ); BN1 stats.
// ---------------------------------------------------------------------------
__global__ __launch_bounds__(256) void k_gemm1(const unsigned short* __restrict__ A,
                                               const unsigned short* __restrict__ W,
                                               const float* __restrict__ bias,
                                               unsigned short* __restrict__ outb,
                                               float* __restrict__ gsum,
                                               float* __restrict__ gsumsq) {
  __shared__ float bsum[DD];
  __shared__ float bsq[DD];
  const int tid = threadIdx.x;
  const int wv = tid >> 6;
  const int lane = tid & 63;
  const int quad = lane >> 4;
  const int l16 = lane & 15;
  if (tid < DD) { bsum[tid] = 0.f; bsq[tid] = 0.f; }
  __syncthreads();

  const int rowbase = blockIdx.x * 64 + wv * 16 + l16;
  const int arow = rowbase < NN ? rowbase : NN - 1;  // clamp; stores guarded
  const unsigned short* aptr = A + (size_t)arow * DD + quad * 8;

  f32x4 acc[8];
#pragma unroll
  for (int n = 0; n < 8; ++n) acc[n] = (f32x4){0.f, 0.f, 0.f, 0.f};

#pragma unroll
  for (int kk = 0; kk < 4; ++kk) {
    const bf16x8 af = *(const bf16x8*)(aptr + kk * 32);
#pragma unroll
    for (int n = 0; n < 8; ++n) {
      const bf16x8 bf =
          *(const bf16x8*)(W + (size_t)(n * 16 + l16) * DD + quad * 8 + kk * 32);
      acc[n] = __builtin_amdgcn_mfma_f32_16x16x32_bf16(af, bf, acc[n], 0, 0, 0);
    }
  }

  const int orow0 = blockIdx.x * 64 + wv * 16 + quad * 4;
#pragma unroll
  for (int n = 0; n < 8; ++n) {
    const int col = n * 16 + l16;
    const float bv = bias[col];
    float s = 0.f, q = 0.f;
#pragma unroll
    for (int r = 0; r < 4; ++r) {
      const int row = orow0 + r;
      if (row < NN) {
        const float o = acc[n][r] + bv;
        outb[(size_t)row * DD + col] = f2bf(o);
        s += o; q += o * o;
      }
    }
    s += __shfl_xor(s, 16); q += __shfl_xor(q, 16);
    s += __shfl_xor(s, 32); q += __shfl_xor(q, 32);
    if (quad == 0) { atomicAdd(&bsum[col], s); atomicAdd(&bsq[col], q); }
  }
  __syncthreads();
  if (tid < DD) {
    atomicAdd(&gsum[tid], bsum[tid]);
    atomicAdd(&gsumsq[tid], bsq[tid]);
  }
}

// ---------------------------------------------------------------------------
// GEMM2: BN1 scale/shift computed in-block; A = relu(BN1(h1b)) on the fly;
// out = h2b bf16 (pre-BN2); BN2 stats.
// ---------------------------------------------------------------------------
__global__ __launch_bounds__(256) void k_gemm2(const unsigned short* __restrict__ A,
                                               const float* __restrict__ sum1,
                                               const float* __restrict__ sumsq1,
                                               const float* __restrict__ gamma,
                                               const float* __restrict__ beta,
                                               const unsigned short* __restrict__ W,
                                               const float* __restrict__ bias,
                                               unsigned short* __restrict__ outb,
                                               float* __restrict__ gsum,
                                               float* __restrict__ gsumsq) {
  __shared__ float lsc[DD];
  __shared__ float lsh[DD];
  __shared__ float bsum[DD];
  __shared__ float bsq[DD];
  const int tid = threadIdx.x;
  const int wv = tid >> 6;
  const int lane = tid & 63;
  const int quad = lane >> 4;
  const int l16 = lane & 15;
  if (tid < DD) {
    const float inv_n = 1.0f / (float)NN;
    const float mean = sum1[tid] * inv_n;
    const float var = sumsq1[tid] * inv_n - mean * mean;
    const float s = gamma[tid] * rsqrtf(var + BN_EPS);
    lsc[tid] = s;
    lsh[tid] = beta[tid] - mean * s;
    bsum[tid] = 0.f;
    bsq[tid] = 0.f;
  }
  __syncthreads();

  const int rowbase = blockIdx.x * 64 + wv * 16 + l16;
  const int arow = rowbase < NN ? rowbase : NN - 1;
  const unsigned short* aptr = A + (size_t)arow * DD + quad * 8;

  f32x4 acc[8];
#pragma unroll
  for (int n = 0; n < 8; ++n) acc[n] = (f32x4){0.f, 0.f, 0.f, 0.f};

#pragma unroll
  for (int kk = 0; kk < 4; ++kk) {
    const int kbase = kk * 32 + quad * 8;
    const u16x8 a = *(const u16x8*)(aptr + kk * 32);
    const float4 s0 = *(const float4*)&lsc[kbase];
    const float4 s1 = *(const float4*)&lsc[kbase + 4];
    const float4 h0 = *(const float4*)&lsh[kbase];
    const float4 h1 = *(const float4*)&lsh[kbase + 4];
    bf16x8 af;
    af[0] = (short)f2bf(fmaxf(fmaf(s0.x, bf2f(a[0]), h0.x), 0.f));
    af[1] = (short)f2bf(fmaxf(fmaf(s0.y, bf2f(a[1]), h0.y), 0.f));
    af[2] = (short)f2bf(fmaxf(fmaf(s0.z, bf2f(a[2]), h0.z), 0.f));
    af[3] = (short)f2bf(fmaxf(fmaf(s0.w, bf2f(a[3]), h0.w), 0.f));
    af[4] = (short)f2bf(fmaxf(fmaf(s1.x, bf2f(a[4]), h1.x), 0.f));
    af[5] = (short)f2bf(fmaxf(fmaf(s1.y, bf2f(a[5]), h1.y), 0.f));
    af[6] = (short)f2bf(fmaxf(fmaf(s1.z, bf2f(a[6]), h1.z), 0.f));
    af[7] = (short)f2bf(fmaxf(fmaf(s1.w, bf2f(a[7]), h1.w), 0.f));
#pragma unroll
    for (int n = 0; n < 8; ++n) {
      const bf16x8 bf =
          *(const bf16x8*)(W + (size_t)(n * 16 + l16) * DD + kbase);
      acc[n] = __builtin_amdgcn_mfma_f32_16x16x32_bf16(af, bf, acc[n], 0, 0, 0);
    }
  }

  const int orow0 = blockIdx.x * 64 + wv * 16 + quad * 4;
#pragma unroll
  for (int n = 0; n < 8; ++n) {
    const int col = n * 16 + l16;
    const float bv = bias[col];
    float s = 0.f, q = 0.f;
#pragma unroll
    for (int r = 0; r < 4; ++r) {
      const int row = orow0 + r;
      if (row < NN) {
        const float o = acc[n][r] + bv;
        outb[(size_t)row * DD + col] = f2bf(o);
        s += o; q += o * o;
      }
    }
    s += __shfl_xor(s, 16); q += __shfl_xor(q, 16);
    s += __shfl_xor(s, 32); q += __shfl_xor(q, 32);
    if (quad == 0) { atomicAdd(&bsum[col], s); atomicAdd(&bsq[col], q); }
  }
  __syncthreads();
  if (tid < DD) {
    atomicAdd(&gsum[tid], bsum[tid]);
    atomicAdd(&gsumsq[tid], bsq[tid]);
  }
}

// K7: final BN2 + ReLU; scale/shift computed in-block from sums.
__global__ __launch_bounds__(256) void k_bnrelu(const unsigned short* __restrict__ in,
                                                const float* __restrict__ sum2,
                                                const float* __restrict__ sumsq2,
                                                const float* __restrict__ gamma,
                                                const float* __restrict__ beta,
                                                float* __restrict__ out) {
  __shared__ float lsc[DD];
  __shared__ float lsh[DD];
  const int t = threadIdx.x;
  if (t < DD) {
    const float inv_n = 1.0f / (float)NN;
    const float mean = sum2[t] * inv_n;
    const float var = sumsq2[t] * inv_n - mean * mean;
    const float s = gamma[t] * rsqrtf(var + BN_EPS);
    lsc[t] = s;
    lsh[t] = beta[t] - mean * s;
  }
  __syncthreads();
  const int gid = blockIdx.x * 256 + t;
  const int c = (gid & 15) * 8;
  const u16x8 a = ((const u16x8*)in)[gid];
  const float4 sc0 = *(const float4*)&lsc[c];
  const float4 sc1 = *(const float4*)&lsc[c + 4];
  const float4 sh0 = *(const float4*)&lsh[c];
  const float4 sh1 = *(const float4*)&lsh[c + 4];
  float4 o0, o1;
  o0.x = fmaxf(fmaf(sc0.x, bf2f(a[0]), sh0.x), 0.f);
  o0.y = fmaxf(fmaf(sc0.y, bf2f(a[1]), sh0.y), 0.f);
  o0.z = fmaxf(fmaf(sc0.z, bf2f(a[2]), sh0.z), 0.f);
  o0.w = fmaxf(fmaf(sc0.w, bf2f(a[3]), sh0.w), 0.f);
  o1.x = fmaxf(fmaf(sc1.x, bf2f(a[4]), sh1.x), 0.f);
  o1.y = fmaxf(fmaf(sc1.y, bf2f(a[5]), sh1.y), 0.f);
  o1.z = fmaxf(fmaf(sc1.z, bf2f(a[6]), sh1.z), 0.f);
  o1.w = fmaxf(fmaf(sc1.w, bf2f(a[7]), sh1.w), 0.f);
  ((float4*)out)[gid * 2] = o0;
  ((float4*)out)[gid * 2 + 1] = o1;
}

// ---------------------------------------------------------------------------
extern "C" void kernel_launch(void* const* d_in, const int* in_sizes, int n_in,
                              void* d_out, int out_size, void* d_ws, size_t ws_size,
                              hipStream_t stream) {
  const float* x = (const float*)d_in[0];
  const int* ei = (const int*)d_in[1];
  const float* eps = (const float*)d_in[2];
  const float* W1 = (const float*)d_in[3];
  const float* b1 = (const float*)d_in[4];
  const float* g1 = (const float*)d_in[5];
  const float* be1 = (const float*)d_in[6];
  const float* W2 = (const float*)d_in[7];
  const float* b2 = (const float*)d_in[8];
  const float* g2 = (const float*)d_in[9];
  const float* be2 = (const float*)d_in[10];
  float* out = (float*)d_out;

  const int* rows = ei;
  const int* cols = ei + EE;

  // d_out scratch (all dead before k_bnrelu writes d_out)
  int* scr = (int*)d_out;
  int* offs = scr;                  // NN+1
  int* cnt = scr + 50008;           // NN
  int* cursor = scr + 100016;       // NN
  int* sc = scr + 150024;           // EE (ends 950024)
  int* partial = scr + 950024;      // 196
  int* bcur = scr + 950240;         // 256
  unsigned short* xb = (unsigned short*)d_out + 2000000;    // byte 4.0M
  int2* pairs = (int2*)((char*)d_out + 16800000);           // byte 16.8M, 6.4MB
  unsigned short* W1b = (unsigned short*)d_out + 11640000;  // byte 23.28M
  unsigned short* W2b = (unsigned short*)d_out + 11680000;  // byte 23.36M

  unsigned short* h0b = (unsigned short*)d_ws;        // region A
  unsigned short* h1b = h0b + (size_t)NN * DD;        // region B
  unsigned short* h2b = h0b;                          // region A (reuse)
  float* stats = (float*)(h0b + (size_t)2 * NN * DD);
  float* sum1 = stats + 0;
  float* sumsq1 = stats + 128;
  float* sum2 = stats + 256;
  float* sumsq2 = stats + 384;

  // 1. fused prep: x/W1/W2 -> bf16, zero cnt+stats
  k_prep<<<XCONV_B + 32, 256, 0, stream>>>(x, W1, W2, xb, W1b, W2b, cnt, stats);
  // 2-6. CSR build (binned two-pass placement)
  k_hist<<<EE / 256, 256, 0, stream>>>(rows, cnt);
  k_scanA<<<SCAN_B, 256, 0, stream>>>(cnt, partial);
  k_scanC<<<SCAN_B, 256, 0, stream>>>(cnt, partial, offs, cursor, bcur);
  k_bin<<<BIN_BLOCKS, 256, 0, stream>>>(rows, cols, bcur, pairs);
  k_place2<<<EE / 256, 256, 0, stream>>>(pairs, cursor, sc);
  // 7. gather aggregation (bf16)
  k_agg<<<NN / 4, 256, 0, stream>>>(xb, eps, offs, sc, h0b);
  // 8-9. fused GEMM+BN layers
  const int gblocks = (NN + 63) / 64;  // 782
  k_gemm1<<<gblocks, 256, 0, stream>>>(h0b, W1b, b1, h1b, sum1, sumsq1);
  k_gemm2<<<gblocks, 256, 0, stream>>>(h1b, sum1, sumsq1, g1, be1, W2b, b2, h2b,
                                       sum2, sumsq2);
  // 10. final BN2+ReLU -> fp32 out
  k_bnrelu<<<(NN * DD / 8) / 256, 256, 0, stream>>>(h2b, sum2, sumsq2, g2, be2, out);
}

// Round 7
// 265.773 us; speedup vs baseline: 5.9497x; 1.0855x over previous
//
#include <hip/hip_runtime.h>

#define NN 50000
#define EE 800000
#define DD 128
#define BN_EPS 1e-5f
#define SCAN_B 196   // ceil(50000/256)
#define XCONV_B 3125 // N*D/8/256
#define BIN_BLOCKS 200
#define BIN_EDGES 4000  // per block; 200*4000 == EE
#define NREP 32         // BN-stat replica count (atomic de-contention)

typedef __attribute__((ext_vector_type(8))) short bf16x8;
typedef __attribute__((ext_vector_type(4))) float f32x4;
typedef __attribute__((ext_vector_type(8))) unsigned short u16x8;

__device__ inline unsigned short f2bf(float f) {  // RNE fp32 -> bf16
  unsigned int u = __float_as_uint(f);
  u = (u + 0x7fffu + ((u >> 16) & 1u)) >> 16;
  return (unsigned short)u;
}
__device__ inline float bf2f(unsigned short b) {
  return __uint_as_float(((unsigned int)b) << 16);
}

// ---------------------------------------------------------------------------
// Memory plan (byte offsets into d_out, 25.6MB):
//   [0, 3.81M)      int scratch: offs | cnt +50008i | cursor +100016i |
//                   sc +150024i | partial +950024i | bcur +950240i
//   [4.0M, 16.8M)   xb  = bf16(x)          (dies after k_agg)
//   [16.8M, 23.2M)  pairs = int2[EE]       (dies after k_place2)
//   [23.28M,+32KB)  W1b; [23.36M,+32KB) W2b
//   [23.5M, +64KB)  reps: sum1[NREP][128] | sumsq1 | sum2 | sumsq2
//   d_out is only overwritten (as fp32 out) by the final k_bnrelu; sum2/sumsq2
//   replicas are collapsed into d_ws by k_bnstats2 BEFORE k_bnrelu runs.
// d_ws (25.6MB + 4KB): region A h0b->h2b | region B h1b |
//   stats at +25.6M: scale2[128] | shift2[128]
// 11 dispatches.
// ---------------------------------------------------------------------------

// K0: fused prep — x->bf16, W1->bf16, W2->bf16, zero cnt + stat replicas
__global__ __launch_bounds__(256) void k_prep(const float* __restrict__ x,
                                              const float* __restrict__ W1,
                                              const float* __restrict__ W2,
                                              unsigned short* __restrict__ xb,
                                              unsigned short* __restrict__ W1b,
                                              unsigned short* __restrict__ W2b,
                                              int* __restrict__ cnt,
                                              float* __restrict__ reps) {
  const int b = blockIdx.x;
  const int t = threadIdx.x;
  if (b < XCONV_B) {
    const int gid = b * 256 + t;
    const float4 v0 = ((const float4*)x)[gid * 2];
    const float4 v1 = ((const float4*)x)[gid * 2 + 1];
    ushort4 o0, o1;
    o0.x = f2bf(v0.x); o0.y = f2bf(v0.y); o0.z = f2bf(v0.z); o0.w = f2bf(v0.w);
    o1.x = f2bf(v1.x); o1.y = f2bf(v1.y); o1.z = f2bf(v1.z); o1.w = f2bf(v1.w);
    ((ushort4*)xb)[gid * 2] = o0;
    ((ushort4*)xb)[gid * 2 + 1] = o1;
    if (gid < NN) cnt[gid] = 0;
    if (gid < 4 * NREP * DD) reps[gid] = 0.0f;  // 16384 floats
  } else if (b < XCONV_B + 16) {
    const int gid = (b - XCONV_B) * 256 + t;
    const float4 v = ((const float4*)W1)[gid];
    ushort4 o;
    o.x = f2bf(v.x); o.y = f2bf(v.y); o.z = f2bf(v.z); o.w = f2bf(v.w);
    ((ushort4*)W1b)[gid] = o;
  } else {
    const int gid = (b - XCONV_B - 16) * 256 + t;
    const float4 v = ((const float4*)W2)[gid];
    ushort4 o;
    o.x = f2bf(v.x); o.y = f2bf(v.y); o.z = f2bf(v.z); o.w = f2bf(v.w);
    ((ushort4*)W2b)[gid] = o;
  }
}

// K1: in-degree histogram
__global__ __launch_bounds__(256) void k_hist(const int* __restrict__ rows,
                                              int* __restrict__ cnt) {
  const int e = blockIdx.x * 256 + threadIdx.x;
  if (e < EE) atomicAdd(&cnt[rows[e]], 1);
}

// K2a: per-chunk reduce
__global__ __launch_bounds__(256) void k_scanA(const int* __restrict__ cnt,
                                               int* __restrict__ partial) {
  __shared__ int red[256];
  const int t = threadIdx.x;
  const int i = blockIdx.x * 256 + t;
  red[t] = (i < NN) ? cnt[i] : 0;
  __syncthreads();
#pragma unroll
  for (int off = 128; off > 0; off >>= 1) {
    if (t < off) red[t] += red[t + off];
    __syncthreads();
  }
  if (t == 0) partial[blockIdx.x] = red[0];
}

// K2b: per-chunk scan; also exports bucket base (bcur) for k_bin.
__global__ __launch_bounds__(256) void k_scanC(const int* __restrict__ cnt,
                                               const int* __restrict__ partial,
                                               int* __restrict__ offs,
                                               int* __restrict__ cursor,
                                               int* __restrict__ bcur) {
  __shared__ int s[256];
  __shared__ int base_s;
  const int t = threadIdx.x;
  const int b = blockIdx.x;
  s[t] = (t < SCAN_B && t < b) ? partial[t] : 0;
  __syncthreads();
#pragma unroll
  for (int off = 128; off > 0; off >>= 1) {
    if (t < off) s[t] += s[t + off];
    __syncthreads();
  }
  if (t == 0) base_s = s[0];
  __syncthreads();
  const int base = base_s;
  __syncthreads();
  const int i = b * 256 + t;
  const int own = (i < NN) ? cnt[i] : 0;
  s[t] = own;
  __syncthreads();
#pragma unroll
  for (int off = 1; off < 256; off <<= 1) {
    const int v = (t >= off) ? s[t - off] : 0;
    __syncthreads();
    s[t] += v;
    __syncthreads();
  }
  if (i < NN) {
    const int o = base + s[t] - own;
    offs[i] = o;
    cursor[i] = o;
  }
  if (t == 0) bcur[b] = base;
  if (b == 0 && t == 0) offs[NN] = EE;
}

// K3a: bin edges into bucket-contiguous (row,col) pairs.
__global__ __launch_bounds__(256) void k_bin(const int* __restrict__ rows,
                                             const int* __restrict__ cols,
                                             int* __restrict__ bcur,
                                             int2* __restrict__ pairs) {
  __shared__ int hist[256];
  __shared__ int lbase[256];
  const int t = threadIdx.x;
  const int e0 = blockIdx.x * BIN_EDGES;
  hist[t] = 0;
  __syncthreads();
  int er[16], ec[16];
#pragma unroll
  for (int i = 0; i < 16; ++i) {
    const int idx = t + i * 256;
    if (idx < BIN_EDGES) {
      er[i] = rows[e0 + idx];
      ec[i] = cols[e0 + idx];
      atomicAdd(&hist[er[i] >> 8], 1);
    }
  }
  __syncthreads();
  const int c = hist[t];
  __syncthreads();
  if (c > 0) lbase[t] = atomicAdd(&bcur[t], c);
  hist[t] = 0;
  __syncthreads();
#pragma unroll
  for (int i = 0; i < 16; ++i) {
    const int idx = t + i * 256;
    if (idx < BIN_EDGES) {
      const int bk = er[i] >> 8;
      const int lp = atomicAdd(&hist[bk], 1);
      pairs[lbase[bk] + lp] = make_int2(er[i], ec[i]);
    }
  }
}

// K3b: final placement from bucket-ordered pairs.
__global__ __launch_bounds__(256) void k_place2(const int2* __restrict__ pairs,
                                                int* __restrict__ cursor,
                                                int* __restrict__ sc) {
  const int i = blockIdx.x * 256 + threadIdx.x;
  const int2 p = pairs[i];
  const int pos = atomicAdd(&cursor[p.x], 1);
  sc[pos] = p.y;
}

// K4: bf16 gather aggregation. One 64-lane wave per dest row.
__global__ __launch_bounds__(256) void k_agg(const unsigned short* __restrict__ xb,
                                             const float* __restrict__ eps,
                                             const int* __restrict__ offs,
                                             const int* __restrict__ sc,
                                             unsigned short* __restrict__ h0b) {
  const int wv = threadIdx.x >> 6;
  const int lane = threadIdx.x & 63;
  const int sub = lane >> 4;
  const int l16 = lane & 15;
  const int v = blockIdx.x * 4 + wv;
  const int beg = offs[v];
  const int end = offs[v + 1];

  float acc[8];
  if (sub == 0) {
    const float s = 1.0f + eps[0];
    const u16x8 a = *(const u16x8*)(xb + (size_t)v * DD + l16 * 8);
#pragma unroll
    for (int j = 0; j < 8; ++j) acc[j] = s * bf2f(a[j]);
  } else {
#pragma unroll
    for (int j = 0; j < 8; ++j) acc[j] = 0.f;
  }

  int i = beg + sub;
  for (; i + 4 < end; i += 8) {
    const int u0 = sc[i];
    const int u1 = sc[i + 4];
    const u16x8 a = *(const u16x8*)(xb + (size_t)u0 * DD + l16 * 8);
    const u16x8 b = *(const u16x8*)(xb + (size_t)u1 * DD + l16 * 8);
#pragma unroll
    for (int j = 0; j < 8; ++j) acc[j] += bf2f(a[j]) + bf2f(b[j]);
  }
  if (i < end) {
    const int u = sc[i];
    const u16x8 a = *(const u16x8*)(xb + (size_t)u * DD + l16 * 8);
#pragma unroll
    for (int j = 0; j < 8; ++j) acc[j] += bf2f(a[j]);
  }

#pragma unroll
  for (int j = 0; j < 8; ++j) {
    acc[j] += __shfl_xor(acc[j], 16);
    acc[j] += __shfl_xor(acc[j], 32);
  }
  if (sub == 0) {
    u16x8 o;
#pragma unroll
    for (int j = 0; j < 8; ++j) o[j] = f2bf(acc[j]);
    *(u16x8*)(h0b + (size_t)v * DD + l16 * 8) = o;
  }
}

// ---------------------------------------------------------------------------
// GEMM1: h1b = bf16(h0b @ W1^T + b1); BN1 stats into replica blockIdx&31.
// ---------------------------------------------------------------------------
__global__ __launch_bounds__(256) void k_gemm1(const unsigned short* __restrict__ A,
                                               const unsigned short* __restrict__ W,
                                               const float* __restrict__ bias,
                                               unsigned short* __restrict__ outb,
                                               float* __restrict__ sum1r,
                                               float* __restrict__ sumsq1r) {
  __shared__ float bsum[DD];
  __shared__ float bsq[DD];
  const int tid = threadIdx.x;
  const int wv = tid >> 6;
  const int lane = tid & 63;
  const int quad = lane >> 4;
  const int l16 = lane & 15;
  if (tid < DD) { bsum[tid] = 0.f; bsq[tid] = 0.f; }
  __syncthreads();

  const int rowbase = blockIdx.x * 64 + wv * 16 + l16;
  const int arow = rowbase < NN ? rowbase : NN - 1;
  const unsigned short* aptr = A + (size_t)arow * DD + quad * 8;

  f32x4 acc[8];
#pragma unroll
  for (int n = 0; n < 8; ++n) acc[n] = (f32x4){0.f, 0.f, 0.f, 0.f};

#pragma unroll
  for (int kk = 0; kk < 4; ++kk) {
    const bf16x8 af = *(const bf16x8*)(aptr + kk * 32);
#pragma unroll
    for (int n = 0; n < 8; ++n) {
      const bf16x8 bf =
          *(const bf16x8*)(W + (size_t)(n * 16 + l16) * DD + quad * 8 + kk * 32);
      acc[n] = __builtin_amdgcn_mfma_f32_16x16x32_bf16(af, bf, acc[n], 0, 0, 0);
    }
  }

  const int orow0 = blockIdx.x * 64 + wv * 16 + quad * 4;
#pragma unroll
  for (int n = 0; n < 8; ++n) {
    const int col = n * 16 + l16;
    const float bv = bias[col];
    float s = 0.f, q = 0.f;
#pragma unroll
    for (int r = 0; r < 4; ++r) {
      const int row = orow0 + r;
      if (row < NN) {
        const float o = acc[n][r] + bv;
        outb[(size_t)row * DD + col] = f2bf(o);
        s += o; q += o * o;
      }
    }
    s += __shfl_xor(s, 16); q += __shfl_xor(q, 16);
    s += __shfl_xor(s, 32); q += __shfl_xor(q, 32);
    if (quad == 0) { atomicAdd(&bsum[col], s); atomicAdd(&bsq[col], q); }
  }
  __syncthreads();
  if (tid < DD) {
    const int rep = (blockIdx.x & (NREP - 1)) * DD;
    atomicAdd(&sum1r[rep + tid], bsum[tid]);
    atomicAdd(&sumsq1r[rep + tid], bsq[tid]);
  }
}

// ---------------------------------------------------------------------------
// GEMM2: collapse sum1 replicas -> BN1 scale/shift in-block; A = relu(BN1(h1b))
// on the fly; out = h2b bf16; BN2 stats into replicas.
// ---------------------------------------------------------------------------
__global__ __launch_bounds__(256) void k_gemm2(const unsigned short* __restrict__ A,
                                               const float* __restrict__ sum1r,
                                               const float* __restrict__ sumsq1r,
                                               const float* __restrict__ gamma,
                                               const float* __restrict__ beta,
                                               const unsigned short* __restrict__ W,
                                               const float* __restrict__ bias,
                                               unsigned short* __restrict__ outb,
                                               float* __restrict__ sum2r,
                                               float* __restrict__ sumsq2r) {
  __shared__ float lsc[DD];
  __shared__ float lsh[DD];
  __shared__ float bsum[DD];
  __shared__ float bsq[DD];
  const int tid = threadIdx.x;
  const int wv = tid >> 6;
  const int lane = tid & 63;
  const int quad = lane >> 4;
  const int l16 = lane & 15;
  if (tid < DD) {
    float sm = 0.f, qm = 0.f;
#pragma unroll
    for (int r = 0; r < NREP; ++r) {
      sm += sum1r[r * DD + tid];
      qm += sumsq1r[r * DD + tid];
    }
    const float inv_n = 1.0f / (float)NN;
    const float mean = sm * inv_n;
    const float var = qm * inv_n - mean * mean;
    const float s = gamma[tid] * rsqrtf(var + BN_EPS);
    lsc[tid] = s;
    lsh[tid] = beta[tid] - mean * s;
    bsum[tid] = 0.f;
    bsq[tid] = 0.f;
  }
  __syncthreads();

  const int rowbase = blockIdx.x * 64 + wv * 16 + l16;
  const int arow = rowbase < NN ? rowbase : NN - 1;
  const unsigned short* aptr = A + (size_t)arow * DD + quad * 8;

  f32x4 acc[8];
#pragma unroll
  for (int n = 0; n < 8; ++n) acc[n] = (f32x4){0.f, 0.f, 0.f, 0.f};

#pragma unroll
  for (int kk = 0; kk < 4; ++kk) {
    const int kbase = kk * 32 + quad * 8;
    const u16x8 a = *(const u16x8*)(aptr + kk * 32);
    const float4 s0 = *(const float4*)&lsc[kbase];
    const float4 s1 = *(const float4*)&lsc[kbase + 4];
    const float4 h0 = *(const float4*)&lsh[kbase];
    const float4 h1 = *(const float4*)&lsh[kbase + 4];
    bf16x8 af;
    af[0] = (short)f2bf(fmaxf(fmaf(s0.x, bf2f(a[0]), h0.x), 0.f));
    af[1] = (short)f2bf(fmaxf(fmaf(s0.y, bf2f(a[1]), h0.y), 0.f));
    af[2] = (short)f2bf(fmaxf(fmaf(s0.z, bf2f(a[2]), h0.z), 0.f));
    af[3] = (short)f2bf(fmaxf(fmaf(s0.w, bf2f(a[3]), h0.w), 0.f));
    af[4] = (short)f2bf(fmaxf(fmaf(s1.x, bf2f(a[4]), h1.x), 0.f));
    af[5] = (short)f2bf(fmaxf(fmaf(s1.y, bf2f(a[5]), h1.y), 0.f));
    af[6] = (short)f2bf(fmaxf(fmaf(s1.z, bf2f(a[6]), h1.z), 0.f));
    af[7] = (short)f2bf(fmaxf(fmaf(s1.w, bf2f(a[7]), h1.w), 0.f));
#pragma unroll
    for (int n = 0; n < 8; ++n) {
      const bf16x8 bf =
          *(const bf16x8*)(W + (size_t)(n * 16 + l16) * DD + kbase);
      acc[n] = __builtin_amdgcn_mfma_f32_16x16x32_bf16(af, bf, acc[n], 0, 0, 0);
    }
  }

  const int orow0 = blockIdx.x * 64 + wv * 16 + quad * 4;
#pragma unroll
  for (int n = 0; n < 8; ++n) {
    const int col = n * 16 + l16;
    const float bv = bias[col];
    float s = 0.f, q = 0.f;
#pragma unroll
    for (int r = 0; r < 4; ++r) {
      const int row = orow0 + r;
      if (row < NN) {
        const float o = acc[n][r] + bv;
        outb[(size_t)row * DD + col] = f2bf(o);
        s += o; q += o * o;
      }
    }
    s += __shfl_xor(s, 16); q += __shfl_xor(q, 16);
    s += __shfl_xor(s, 32); q += __shfl_xor(q, 32);
    if (quad == 0) { atomicAdd(&bsum[col], s); atomicAdd(&bsq[col], q); }
  }
  __syncthreads();
  if (tid < DD) {
    const int rep = (blockIdx.x & (NREP - 1)) * DD;
    atomicAdd(&sum2r[rep + tid], bsum[tid]);
    atomicAdd(&sumsq2r[rep + tid], bsq[tid]);
  }
}

// K6: collapse sum2 replicas -> BN2 scale/shift in d_ws (BEFORE bnrelu
// overwrites d_out, where the replicas live).
__global__ void k_bnstats2(const float* __restrict__ sum2r,
                           const float* __restrict__ sumsq2r,
                           const float* __restrict__ gamma,
                           const float* __restrict__ beta,
                           float* __restrict__ scale,
                           float* __restrict__ shift) {
  const int c = threadIdx.x;
  float sm = 0.f, qm = 0.f;
#pragma unroll
  for (int r = 0; r < NREP; ++r) {
    sm += sum2r[r * DD + c];
    qm += sumsq2r[r * DD + c];
  }
  const float inv_n = 1.0f / (float)NN;
  const float mean = sm * inv_n;
  const float var = qm * inv_n - mean * mean;
  const float sc = gamma[c] * rsqrtf(var + BN_EPS);
  scale[c] = sc;
  shift[c] = beta[c] - mean * sc;
}

// K7: final BN2 + ReLU
__global__ __launch_bounds__(256) void k_bnrelu(const unsigned short* __restrict__ in,
                                                const float* __restrict__ scale,
                                                const float* __restrict__ shift,
                                                float* __restrict__ out) {
  __shared__ float lsc[DD];
  __shared__ float lsh[DD];
  const int t = threadIdx.x;
  if (t < DD) {
    lsc[t] = scale[t];
    lsh[t] = shift[t];
  }
  __syncthreads();
  const int gid = blockIdx.x * 256 + t;
  const int c = (gid & 15) * 8;
  const u16x8 a = ((const u16x8*)in)[gid];
  const float4 sc0 = *(const float4*)&lsc[c];
  const float4 sc1 = *(const float4*)&lsc[c + 4];
  const float4 sh0 = *(const float4*)&lsh[c];
  const float4 sh1 = *(const float4*)&lsh[c + 4];
  float4 o0, o1;
  o0.x = fmaxf(fmaf(sc0.x, bf2f(a[0]), sh0.x), 0.f);
  o0.y = fmaxf(fmaf(sc0.y, bf2f(a[1]), sh0.y), 0.f);
  o0.z = fmaxf(fmaf(sc0.z, bf2f(a[2]), sh0.z), 0.f);
  o0.w = fmaxf(fmaf(sc0.w, bf2f(a[3]), sh0.w), 0.f);
  o1.x = fmaxf(fmaf(sc1.x, bf2f(a[4]), sh1.x), 0.f);
  o1.y = fmaxf(fmaf(sc1.y, bf2f(a[5]), sh1.y), 0.f);
  o1.z = fmaxf(fmaf(sc1.z, bf2f(a[6]), sh1.z), 0.f);
  o1.w = fmaxf(fmaf(sc1.w, bf2f(a[7]), sh1.w), 0.f);
  ((float4*)out)[gid * 2] = o0;
  ((float4*)out)[gid * 2 + 1] = o1;
}

// ---------------------------------------------------------------------------
extern "C" void kernel_launch(void* const* d_in, const int* in_sizes, int n_in,
                              void* d_out, int out_size, void* d_ws, size_t ws_size,
                              hipStream_t stream) {
  const float* x = (const float*)d_in[0];
  const int* ei = (const int*)d_in[1];
  const float* eps = (const float*)d_in[2];
  const float* W1 = (const float*)d_in[3];
  const float* b1 = (const float*)d_in[4];
  const float* g1 = (const float*)d_in[5];
  const float* be1 = (const float*)d_in[6];
  const float* W2 = (const float*)d_in[7];
  const float* b2 = (const float*)d_in[8];
  const float* g2 = (const float*)d_in[9];
  const float* be2 = (const float*)d_in[10];
  float* out = (float*)d_out;

  const int* rows = ei;
  const int* cols = ei + EE;

  // d_out scratch (all dead before k_bnrelu writes d_out)
  int* scr = (int*)d_out;
  int* offs = scr;                  // NN+1
  int* cnt = scr + 50008;           // NN
  int* cursor = scr + 100016;       // NN
  int* sc = scr + 150024;           // EE (ends 950024)
  int* partial = scr + 950024;      // 196
  int* bcur = scr + 950240;         // 256
  unsigned short* xb = (unsigned short*)d_out + 2000000;    // byte 4.0M
  int2* pairs = (int2*)((char*)d_out + 16800000);           // byte 16.8M, 6.4MB
  unsigned short* W1b = (unsigned short*)d_out + 11640000;  // byte 23.28M
  unsigned short* W2b = (unsigned short*)d_out + 11680000;  // byte 23.36M
  float* reps = (float*)d_out + 5875000;                    // byte 23.5M, 64KB
  float* sum1r = reps;                // NREP*128
  float* sumsq1r = reps + NREP * DD;  // NREP*128
  float* sum2r = reps + 2 * NREP * DD;
  float* sumsq2r = reps + 3 * NREP * DD;

  unsigned short* h0b = (unsigned short*)d_ws;        // region A
  unsigned short* h1b = h0b + (size_t)NN * DD;        // region B
  unsigned short* h2b = h0b;                          // region A (reuse)
  float* stats = (float*)(h0b + (size_t)2 * NN * DD); // 4KB in d_ws
  float* scale2 = stats + 0;
  float* shift2 = stats + 128;

  // 1. fused prep: x/W1/W2 -> bf16, zero cnt + stat replicas
  k_prep<<<XCONV_B + 32, 256, 0, stream>>>(x, W1, W2, xb, W1b, W2b, cnt, reps);
  // 2-6. CSR build (binned two-pass placement)
  k_hist<<<EE / 256, 256, 0, stream>>>(rows, cnt);
  k_scanA<<<SCAN_B, 256, 0, stream>>>(cnt, partial);
  k_scanC<<<SCAN_B, 256, 0, stream>>>(cnt, partial, offs, cursor, bcur);
  k_bin<<<BIN_BLOCKS, 256, 0, stream>>>(rows, cols, bcur, pairs);
  k_place2<<<EE / 256, 256, 0, stream>>>(pairs, cursor, sc);
  // 7. gather aggregation (bf16)
  k_agg<<<NN / 4, 256, 0, stream>>>(xb, eps, offs, sc, h0b);
  // 8-9. fused GEMM+BN layers (replicated stat atomics)
  const int gblocks = (NN + 63) / 64;  // 782
  k_gemm1<<<gblocks, 256, 0, stream>>>(h0b, W1b, b1, h1b, sum1r, sumsq1r);
  k_gemm2<<<gblocks, 256, 0, stream>>>(h1b, sum1r, sumsq1r, g1, be1, W2b, b2,
                                       h2b, sum2r, sumsq2r);
  // 10. collapse BN2 replicas into d_ws (replicas live in d_out!)
  k_bnstats2<<<1, 128, 0, stream>>>(sum2r, sumsq2r, g2, be2, scale2, shift2);
  // 11. final BN2+ReLU -> fp32 out
  k_bnrelu<<<(NN * DD / 8) / 256, 256, 0, stream>>>(h2b, scale2, shift2, out);
}